// Round 6
// baseline (533.856 us; speedup 1.0000x reference)
//
#include <hip/hip_runtime.h>
#include <math.h>

#define HH 256
#define WW 256
#define BATCH 8
#define HWSZ 65536
#define NPB2 4096  // partial slots for conv2/conv3 (4*128*8 blocks)

typedef __attribute__((ext_vector_type(8))) short short8;
typedef __attribute__((ext_vector_type(4))) float floatx4;

__device__ __forceinline__ unsigned short f2bf(float f) {
  union { float f; unsigned int u; } v; v.f = f;
  unsigned int r = v.u + 0x7fff + ((v.u >> 16) & 1);
  return (unsigned short)(r >> 16);
}
__device__ __forceinline__ float bf2f(unsigned short u) {
  union { unsigned int u; float f; } v; v.u = ((unsigned int)u) << 16;
  return v.f;
}

// ---- fused weight pre-swizzle for conv2+conv3: OIHW fp32 -> B-frag bf16 ---
__global__ __launch_bounds__(256) void prep_all(
    const float* __restrict__ w2, const float* __restrict__ w3,
    unsigned short* __restrict__ wf2, unsigned short* __restrict__ wf3)
{
  int idx = blockIdx.x * 256 + threadIdx.x;
  if (idx < 18432) {  // conv2: CIN=32, COUT=64, KC=1, NG=4
    const int j = idx & 7;
    const int lane = (idx >> 3) & 63;
    int rest = idx >> 9;
    const int ng = rest % 4;
    const int tap = rest / 4;
    const int cout = ng * 16 + (lane & 15);
    const int cin = ((lane >> 4) << 3) + j;
    wf2[idx] = f2bf(w2[((size_t)cout * 32 + cin) * 9 + tap]);
  } else {            // conv3: CIN=64, COUT=128, KC=2, NG=8
    idx -= 18432;
    if (idx >= 73728) return;
    const int j = idx & 7;
    const int lane = (idx >> 3) & 63;
    int rest = idx >> 9;
    const int ng = rest % 8; rest /= 8;
    const int kc = rest & 1;
    const int tap = rest >> 1;
    const int cout = ng * 16 + (lane & 15);
    const int cin = kc * 32 + ((lane >> 4) << 3) + j;
    wf3[idx] = f2bf(w3[((size_t)cout * 64 + cin) * 9 + tap]);
  }
}

// ---- conv1: 3->32, fp32 VALU, raw y1 (bias, NO bn) bf16 NHWC direct store -
__global__ __launch_bounds__(256) void conv1_kernel(
    const float* __restrict__ in, const float* __restrict__ wgt,
    const float* __restrict__ bias, unsigned short* __restrict__ out,
    float* __restrict__ partial)
{
  const int w = threadIdx.x, h = blockIdx.x, b = blockIdx.y;
  int off[9]; float msk[9];
  #pragma unroll
  for (int dh = -1; dh <= 1; ++dh)
    #pragma unroll
    for (int dw = -1; dw <= 1; ++dw) {
      int t9 = (dh + 1) * 3 + (dw + 1);
      int hh = h + dh, ww = w + dw;
      bool ok = (hh >= 0) && (hh < HH) && (ww >= 0) && (ww < WW);
      int hc = min(max(hh, 0), HH - 1), wc = min(max(ww, 0), WW - 1);
      off[t9] = hc * WW + wc;
      msk[t9] = ok ? 1.0f : 0.0f;
    }
  const float* inb = in + (size_t)b * 3 * HWSZ;
  float acc[32];
  #pragma unroll
  for (int c = 0; c < 32; ++c) acc[c] = bias[c];
  for (int ci = 0; ci < 3; ++ci) {
    const float* p = inb + (size_t)ci * HWSZ;
    float v[9];
    #pragma unroll
    for (int t = 0; t < 9; ++t) v[t] = p[off[t]] * msk[t];
    #pragma unroll
    for (int c = 0; c < 32; ++c) {
      const float* wr = wgt + ((size_t)c * 3 + ci) * 9;
      #pragma unroll
      for (int t = 0; t < 9; ++t) acc[c] = fmaf(wr[t], v[t], acc[c]);
    }
  }
  __shared__ float red[4][32][2];
  const int lane = threadIdx.x & 63, wv = threadIdx.x >> 6;
  #pragma unroll
  for (int c = 0; c < 32; ++c) {
    float s = acc[c], q = acc[c] * acc[c];
    #pragma unroll
    for (int o = 32; o > 0; o >>= 1) { s += __shfl_down(s, o); q += __shfl_down(q, o); }
    if (lane == 0) { red[wv][c][0] = s; red[wv][c][1] = q; }
  }
  uint4* o4 = (uint4*)(out + ((size_t)((b * 256 + h) * 256 + w)) * 32);
  #pragma unroll
  for (int i = 0; i < 4; ++i) {
    uint4 u;
    u.x = (unsigned int)f2bf(acc[8 * i + 0]) | ((unsigned int)f2bf(acc[8 * i + 1]) << 16);
    u.y = (unsigned int)f2bf(acc[8 * i + 2]) | ((unsigned int)f2bf(acc[8 * i + 3]) << 16);
    u.z = (unsigned int)f2bf(acc[8 * i + 4]) | ((unsigned int)f2bf(acc[8 * i + 5]) << 16);
    u.w = (unsigned int)f2bf(acc[8 * i + 6]) | ((unsigned int)f2bf(acc[8 * i + 7]) << 16);
    o4[i] = u;
  }
  __syncthreads();
  if (threadIdx.x < 64) {
    int c = threadIdx.x >> 1, j = threadIdx.x & 1;
    float r = red[0][c][j] + red[1][c][j] + red[2][c][j] + red[3][c][j];
    int pb = b * 256 + h;
    partial[((size_t)c * 2 + j) * 2048 + pb] = r;
  }
}

// ---- MFMA conv: 64px x 2 rows x COUT per block, RAW input + fused BN ------
// Stage 4 rows x 66 px once (BN+lrelu applied on unpack), ONE barrier, then
// 2 output rows sequentially. XOR-swizzled LDS (2-way only = free).
// Stats of (conv+bias, pre-BN) in regs -> LDS-reused reduction -> partial.
template<int CIN, int COUT, bool WRITE_OUT, int MINW>
__global__ __launch_bounds__(256, MINW) void conv_mfma(
    const unsigned short* __restrict__ in, const unsigned short* __restrict__ wf,
    const float* __restrict__ bias,
    const float* __restrict__ bn_sc, const float* __restrict__ bn_sh,
    unsigned short* __restrict__ out, float* __restrict__ partial)
{
  constexpr int KC = CIN / 32;
  constexpr int NG = COUT / 16;
  constexpr int NF = COUT / 32;       // n-frags per wave (2 n-waves)
  constexpr int CH8 = CIN / 8;        // 16B chunks per pixel
  constexpr int CH8_LOG = (CH8 == 4) ? 2 : 3;
  constexpr int ROWSZ = 66 * CIN;     // halfwords per LDS row slot

  const int tid = threadIdx.x, lane = tid & 63, wv = tid >> 6;
  const int wave_m = wv >> 1, wave_n = wv & 1;
  const int h0 = blockIdx.y * 2, b = blockIdx.z, w0 = blockIdx.x * 64;
  const size_t inb = (size_t)b * HWSZ * CIN;

  __shared__ __align__(16) unsigned short lds[4 * ROWSZ];

  // stage 4 rows x 66 px, applying BN(scale/shift)+leakyReLU on unpack
  for (int c = tid; c < 4 * 66 * CH8; c += 256) {
    const int r = c / (66 * CH8);
    const int rem = c - r * (66 * CH8);
    const int px = rem >> CH8_LOG, ck = rem & (CH8 - 1);
    const int hi = h0 + r - 1, wi = w0 - 1 + px;
    uint4 v = make_uint4(0u, 0u, 0u, 0u);
    if ((unsigned)hi < 256u && (unsigned)wi < 256u) {
      uint4 raw = *(const uint4*)&in[inb + ((size_t)hi * 256 + wi) * CIN + ck * 8];
      const float4 s0 = *(const float4*)&bn_sc[ck * 8];
      const float4 s1 = *(const float4*)&bn_sc[ck * 8 + 4];
      const float4 t0 = *(const float4*)&bn_sh[ck * 8];
      const float4 t1 = *(const float4*)&bn_sh[ck * 8 + 4];
      const float scs[8] = {s0.x, s0.y, s0.z, s0.w, s1.x, s1.y, s1.z, s1.w};
      const float shs[8] = {t0.x, t0.y, t0.z, t0.w, t1.x, t1.y, t1.z, t1.w};
      unsigned int* u = (unsigned int*)&raw;
      unsigned int* o = (unsigned int*)&v;
      #pragma unroll
      for (int p = 0; p < 4; ++p) {
        float a = bf2f((unsigned short)(u[p] & 0xffff));
        float d = bf2f((unsigned short)(u[p] >> 16));
        float ya = a * scs[2 * p] + shs[2 * p];
        float yd = d * scs[2 * p + 1] + shs[2 * p + 1];
        ya = fmaxf(ya, 0.01f * ya);
        yd = fmaxf(yd, 0.01f * yd);
        o[p] = (unsigned int)f2bf(ya) | ((unsigned int)f2bf(yd) << 16);
      }
    }
    const int sw = ck ^ (px & (CH8 - 1)) ^ ((px >> CH8_LOG) & (CH8 - 1));
    *(uint4*)&lds[(r * 66 + px) * CIN + sw * 8] = v;
  }
  __syncthreads();

  const int j15 = lane & 15, q4 = lane >> 4;
  const int base_px = wave_m * 32 + j15;

  float bv[NF], sa[NF], qa[NF];
  #pragma unroll
  for (int nf = 0; nf < NF; ++nf) {
    bv[nf] = bias[wave_n * (COUT / 2) + nf * 16 + j15];
    sa[nf] = 0.f; qa[nf] = 0.f;
  }

  #pragma unroll
  for (int rr = 0; rr < 2; ++rr) {
    floatx4 acc[2][NF];
    #pragma unroll
    for (int mf = 0; mf < 2; ++mf)
      #pragma unroll
      for (int nf = 0; nf < NF; ++nf) acc[mf][nf] = (floatx4){0.f, 0.f, 0.f, 0.f};

    #pragma unroll
    for (int dh = 0; dh < 3; ++dh) {
      const int sbase = (rr + dh) * ROWSZ;
      #pragma unroll
      for (int dw = 0; dw < 3; ++dw) {
        #pragma unroll
        for (int kc = 0; kc < KC; ++kc) {
          short8 a[2];
          #pragma unroll
          for (int mf = 0; mf < 2; ++mf) {
            const int p = dw + base_px + mf * 16;        // px slot 0..65
            const int ck = kc * 4 + q4;
            const int sw = ck ^ (p & (CH8 - 1)) ^ ((p >> CH8_LOG) & (CH8 - 1));
            a[mf] = *(const short8*)&lds[sbase + p * CIN + sw * 8];
          }
          const int tap = dh * 3 + dw;
          short8 bg[NF];
          #pragma unroll
          for (int nf = 0; nf < NF; ++nf)
            bg[nf] = *(const short8*)&wf[((((tap * KC + kc) * NG) + wave_n * NF + nf) * 64 + lane) * 8];
          #pragma unroll
          for (int mf = 0; mf < 2; ++mf)
            #pragma unroll
            for (int nf = 0; nf < NF; ++nf)
              acc[mf][nf] = __builtin_amdgcn_mfma_f32_16x16x32_bf16(a[mf], bg[nf], acc[mf][nf], 0, 0, 0);
        }
      }
    }

    // per-row epilogue: +bias, stats in regs, optional raw bf16 NHWC store
    const size_t orow = ((size_t)(b * 256 + (h0 + rr)) * 256 + w0);
    #pragma unroll
    for (int nf = 0; nf < NF; ++nf) {
      const int ch = wave_n * (COUT / 2) + nf * 16 + j15;
      #pragma unroll
      for (int mf = 0; mf < 2; ++mf)
        #pragma unroll
        for (int r4 = 0; r4 < 4; ++r4) {
          float y = acc[mf][nf][r4] + bv[nf];
          sa[nf] += y; qa[nf] += y * y;
          if constexpr (WRITE_OUT) {
            const int p = wave_m * 32 + mf * 16 + q4 * 4 + r4;
            out[(orow + p) * COUT + ch] = f2bf(y);
          }
        }
    }
  }

  // stats reduction, reusing staging LDS
  __syncthreads();
  float* red = (float*)lds;  // [4][NF][16] sums, then [4][NF][16] sumsq
  #pragma unroll
  for (int nf = 0; nf < NF; ++nf) {
    float s = sa[nf], q = qa[nf];
    s += __shfl_xor(s, 16); s += __shfl_xor(s, 32);
    q += __shfl_xor(q, 16); q += __shfl_xor(q, 32);
    if (lane < 16) {
      red[(wv * NF + nf) * 16 + lane] = s;
      red[4 * NF * 16 + (wv * NF + nf) * 16 + lane] = q;
    }
  }
  __syncthreads();
  if (tid < COUT) {
    const int wn = tid / (COUT / 2), rr = tid % (COUT / 2);
    const int nf = rr >> 4, li = rr & 15;
    float s = red[(wn * NF + nf) * 16 + li] + red[((wn + 2) * NF + nf) * 16 + li];
    float q = red[4 * NF * 16 + (wn * NF + nf) * 16 + li] +
              red[4 * NF * 16 + ((wn + 2) * NF + nf) * 16 + li];
    const int blk = blockIdx.x + ((int)blockIdx.z * 128 + (int)blockIdx.y) * 4;  // 0..4095
    partial[((size_t)tid * 2 + 0) * NPB2 + blk] = s;
    partial[((size_t)tid * 2 + 1) * NPB2 + blk] = q;
  }
}

// ---- fold partials into scale/shift ---------------------------------------
__global__ __launch_bounds__(256) void reduce_stats(
    const float* __restrict__ partial, const float* __restrict__ gamma,
    const float* __restrict__ beta, float* __restrict__ scale,
    float* __restrict__ shift, int npb)
{
  const int c = blockIdx.x;
  float s = 0.f, q = 0.f;
  for (int i = threadIdx.x; i < npb; i += 256) {
    s += partial[((size_t)c * 2 + 0) * npb + i];
    q += partial[((size_t)c * 2 + 1) * npb + i];
  }
  #pragma unroll
  for (int o = 32; o > 0; o >>= 1) { s += __shfl_down(s, o); q += __shfl_down(q, o); }
  __shared__ float rs[4][2];
  const int lane = threadIdx.x & 63, wv = threadIdx.x >> 6;
  if (lane == 0) { rs[wv][0] = s; rs[wv][1] = q; }
  __syncthreads();
  if (threadIdx.x == 0) {
    s = rs[0][0] + rs[1][0] + rs[2][0] + rs[3][0];
    q = rs[0][1] + rs[1][1] + rs[2][1] + rs[3][1];
    const float N = (float)((size_t)BATCH * HWSZ);
    float mean = s / N;
    float var = q / N - mean * mean;
    float rstd = 1.0f / sqrtf(var + 1e-5f);
    float sc = gamma[c] * rstd;
    scale[c] = sc;
    shift[c] = beta[c] - mean * sc;
  }
}

// ---- fused outputs: patches (blocks 0..13) + encode (blocks 14..17) -------
// encode: conv3 at 8 pixels (n_xy) on RAW y2 (bn2+lrelu on read), bn3 at end.
__global__ __launch_bounds__(256) void outputs_kernel(
    const float* __restrict__ img, const int* __restrict__ axy,
    const int* __restrict__ pxy, const int* __restrict__ nxy,
    const unsigned short* __restrict__ y2, const float* __restrict__ wgt,
    const float* __restrict__ bias,
    const float* __restrict__ sc2, const float* __restrict__ sh2,
    const float* __restrict__ scale, const float* __restrict__ shift,
    float* __restrict__ out)
{
  if (blockIdx.x < 14) {
    const int i = blockIdx.x * 256 + threadIdx.x;
    if (i >= 3 * BATCH * 3 * 49) return;
    const int arr = i / 1176, r = i % 1176;
    const int b = r / 147, q = r % 147;
    const int c = q / 49, s = q % 49;
    const int ph = s / 7, pw = s % 7;
    const int* xy = (arr == 0) ? axy : ((arr == 1) ? pxy : nxy);
    const int x = xy[(b * 32 + 31) * 2 + 0];
    const int y = xy[(b * 32 + 31) * 2 + 1];
    out[i] = img[((size_t)(b * 3 + c) * HH + (x - 3 + ph)) * WW + (y - 3 + pw)];
  } else {
    const int b = (blockIdx.x - 14) * 2 + (threadIdx.x >> 7);
    const int co = threadIdx.x & 127;
    const int x = nxy[(b * 32 + 31) * 2 + 0];
    const int y = nxy[(b * 32 + 31) * 2 + 1];
    float acc = bias[co];
    for (int ci = 0; ci < 64; ++ci) {
      const float s2 = sc2[ci], h2 = sh2[ci];
      #pragma unroll
      for (int dh = -1; dh <= 1; ++dh)
        #pragma unroll
        for (int dw = -1; dw <= 1; ++dw) {
          float v = bf2f(y2[((size_t)(b * 256 + x + dh) * 256 + (y + dw)) * 64 + ci]);
          v = v * s2 + h2;
          v = fmaxf(v, 0.01f * v);
          acc = fmaf(wgt[((size_t)co * 64 + ci) * 9 + (dh + 1) * 3 + (dw + 1)], v, acc);
        }
    }
    const float yv = acc * scale[co] + shift[co];
    out[3528 + b * 128 + co] = fmaxf(yv, 0.01f * yv);
  }
}

extern "C" void kernel_launch(void* const* d_in, const int* in_sizes, int n_in,
                              void* d_out, int out_size, void* d_ws, size_t ws_size,
                              hipStream_t stream)
{
  const float* image = (const float*)d_in[0];
  const int* axy = (const int*)d_in[1];
  const int* pxy = (const int*)d_in[2];
  const int* nxy = (const int*)d_in[3];
  const float* c1w = (const float*)d_in[4];
  const float* c1b = (const float*)d_in[5];
  const float* g1 = (const float*)d_in[6];
  const float* b1 = (const float*)d_in[7];
  const float* c2w = (const float*)d_in[8];
  const float* c2b = (const float*)d_in[9];
  const float* g2 = (const float*)d_in[10];
  const float* b2 = (const float*)d_in[11];
  const float* c3w = (const float*)d_in[12];
  const float* c3b = (const float*)d_in[13];
  const float* g3 = (const float*)d_in[14];
  const float* b3 = (const float*)d_in[15];
  float* out = (float*)d_out;

  // workspace layout (~105 MB)
  unsigned short* zb1 = (unsigned short*)d_ws;            // raw y1, 16.78M bf16
  unsigned short* zb2 = zb1 + (size_t)8 * 32 * HWSZ;      // raw y2, 33.55M bf16
  unsigned short* wf2 = zb2 + (size_t)8 * 64 * HWSZ;      // 18432
  unsigned short* wf3 = wf2 + 18432;                      // 73728
  float* partial = (float*)(wf3 + 73728);                 // 128*2*4096 floats
  float* scale1 = partial + (size_t)128 * 2 * NPB2;
  float* shift1 = scale1 + 32;
  float* scale2 = shift1 + 32;
  float* shift2 = scale2 + 64;
  float* scale3 = shift2 + 64;
  float* shift3 = scale3 + 128;

  prep_all<<<360, 256, 0, stream>>>(c2w, c3w, wf2, wf3);

  // layer 1: 3 -> 32 (VALU fp32, raw bf16 NHWC out + stats)
  conv1_kernel<<<dim3(256, 8), 256, 0, stream>>>(image, c1w, c1b, zb1, partial);
  reduce_stats<<<32, 256, 0, stream>>>(partial, g1, b1, scale1, shift1, 2048);

  // layer 2: 32 -> 64 (MFMA; bn1+lrelu fused in staging; raw y2 out + stats)
  conv_mfma<32, 64, true, 4><<<dim3(4, 128, 8), 256, 0, stream>>>(
      zb1, wf2, c2b, scale1, shift1, zb2, partial);
  reduce_stats<<<64, 256, 0, stream>>>(partial, g2, b2, scale2, shift2, NPB2);

  // layer 3: 64 -> 128 (MFMA; bn2+lrelu fused in staging; stats only)
  conv_mfma<64, 128, false, 4><<<dim3(4, 128, 8), 256, 0, stream>>>(
      zb2, wf3, c3b, scale2, shift2, nullptr, partial);
  reduce_stats<<<128, 256, 0, stream>>>(partial, g3, b3, scale3, shift3, NPB2);

  // outputs: patches + encode fused (bn2 on reads, bn3 at end)
  outputs_kernel<<<18, 256, 0, stream>>>(image, axy, pxy, nxy, zb2, c3w, c3b,
                                         scale2, shift2, scale3, shift3, out);
}

// Round 7
// 328.968 us; speedup vs baseline: 1.6228x; 1.6228x over previous
//
#include <hip/hip_runtime.h>
#include <math.h>

#define HH 256
#define WW 256
#define BATCH 8
#define HWSZ 65536
#define NPB2 4096  // partial slots for conv2/conv3 (2*256*8 blocks)

typedef __attribute__((ext_vector_type(8))) short short8;
typedef __attribute__((ext_vector_type(4))) float floatx4;

__device__ __forceinline__ unsigned short f2bf(float f) {
  union { float f; unsigned int u; } v; v.f = f;
  unsigned int r = v.u + 0x7fff + ((v.u >> 16) & 1);
  return (unsigned short)(r >> 16);
}
__device__ __forceinline__ float bf2f(unsigned short u) {
  union { unsigned int u; float f; } v; v.u = ((unsigned int)u) << 16;
  return v.f;
}

// ---- fused weight pre-swizzle for conv2+conv3: OIHW fp32 -> B-frag bf16 ---
__global__ __launch_bounds__(256) void prep_all(
    const float* __restrict__ w2, const float* __restrict__ w3,
    unsigned short* __restrict__ wf2, unsigned short* __restrict__ wf3)
{
  int idx = blockIdx.x * 256 + threadIdx.x;
  if (idx < 18432) {  // conv2: CIN=32, COUT=64, KC=1, NG=4
    const int j = idx & 7;
    const int lane = (idx >> 3) & 63;
    int rest = idx >> 9;
    const int ng = rest % 4;
    const int tap = rest / 4;
    const int cout = ng * 16 + (lane & 15);
    const int cin = ((lane >> 4) << 3) + j;
    wf2[idx] = f2bf(w2[((size_t)cout * 32 + cin) * 9 + tap]);
  } else {            // conv3: CIN=64, COUT=128, KC=2, NG=8
    idx -= 18432;
    if (idx >= 73728) return;
    const int j = idx & 7;
    const int lane = (idx >> 3) & 63;
    int rest = idx >> 9;
    const int ng = rest % 8; rest /= 8;
    const int kc = rest & 1;
    const int tap = rest >> 1;
    const int cout = ng * 16 + (lane & 15);
    const int cin = kc * 32 + ((lane >> 4) << 3) + j;
    wf3[idx] = f2bf(w3[((size_t)cout * 64 + cin) * 9 + tap]);
  }
}

// ---- conv1: 3->32, fp32 VALU, raw y1 (bias, NO bn) bf16 NHWC direct store -
__global__ __launch_bounds__(256) void conv1_kernel(
    const float* __restrict__ in, const float* __restrict__ wgt,
    const float* __restrict__ bias, unsigned short* __restrict__ out,
    float* __restrict__ partial)
{
  const int w = threadIdx.x, h = blockIdx.x, b = blockIdx.y;
  int off[9]; float msk[9];
  #pragma unroll
  for (int dh = -1; dh <= 1; ++dh)
    #pragma unroll
    for (int dw = -1; dw <= 1; ++dw) {
      int t9 = (dh + 1) * 3 + (dw + 1);
      int hh = h + dh, ww = w + dw;
      bool ok = (hh >= 0) && (hh < HH) && (ww >= 0) && (ww < WW);
      int hc = min(max(hh, 0), HH - 1), wc = min(max(ww, 0), WW - 1);
      off[t9] = hc * WW + wc;
      msk[t9] = ok ? 1.0f : 0.0f;
    }
  const float* inb = in + (size_t)b * 3 * HWSZ;
  float acc[32];
  #pragma unroll
  for (int c = 0; c < 32; ++c) acc[c] = bias[c];
  for (int ci = 0; ci < 3; ++ci) {
    const float* p = inb + (size_t)ci * HWSZ;
    float v[9];
    #pragma unroll
    for (int t = 0; t < 9; ++t) v[t] = p[off[t]] * msk[t];
    #pragma unroll
    for (int c = 0; c < 32; ++c) {
      const float* wr = wgt + ((size_t)c * 3 + ci) * 9;
      #pragma unroll
      for (int t = 0; t < 9; ++t) acc[c] = fmaf(wr[t], v[t], acc[c]);
    }
  }
  __shared__ float red[4][32][2];
  const int lane = threadIdx.x & 63, wv = threadIdx.x >> 6;
  #pragma unroll
  for (int c = 0; c < 32; ++c) {
    float s = acc[c], q = acc[c] * acc[c];
    #pragma unroll
    for (int o = 32; o > 0; o >>= 1) { s += __shfl_down(s, o); q += __shfl_down(q, o); }
    if (lane == 0) { red[wv][c][0] = s; red[wv][c][1] = q; }
  }
  uint4* o4 = (uint4*)(out + ((size_t)((b * 256 + h) * 256 + w)) * 32);
  #pragma unroll
  for (int i = 0; i < 4; ++i) {
    uint4 u;
    u.x = (unsigned int)f2bf(acc[8 * i + 0]) | ((unsigned int)f2bf(acc[8 * i + 1]) << 16);
    u.y = (unsigned int)f2bf(acc[8 * i + 2]) | ((unsigned int)f2bf(acc[8 * i + 3]) << 16);
    u.z = (unsigned int)f2bf(acc[8 * i + 4]) | ((unsigned int)f2bf(acc[8 * i + 5]) << 16);
    u.w = (unsigned int)f2bf(acc[8 * i + 6]) | ((unsigned int)f2bf(acc[8 * i + 7]) << 16);
    o4[i] = u;
  }
  __syncthreads();
  if (threadIdx.x < 64) {
    int c = threadIdx.x >> 1, j = threadIdx.x & 1;
    float r = red[0][c][j] + red[1][c][j] + red[2][c][j] + red[3][c][j];
    int pb = b * 256 + h;
    partial[((size_t)c * 2 + j) * 2048 + pb] = r;
  }
}

// ---- MFMA conv (R4 structure): 1 row of 128px x COUT per block ------------
// RAW input; BN+lrelu fused into staging unpack. XOR-swizzled LDS (measured
// 0 conflicts). Staging loop fully unrolled (compile-time ITERS) so the
// independent global loads batch-issue and their latency overlaps the unpack.
template<int CIN, int COUT, bool WRITE_OUT, int MINW>
__global__ __launch_bounds__(256, MINW) void conv_mfma(
    const unsigned short* __restrict__ in, const unsigned short* __restrict__ wf,
    const float* __restrict__ bias,
    const float* __restrict__ bn_sc, const float* __restrict__ bn_sh,
    unsigned short* __restrict__ out, float* __restrict__ partial)
{
  constexpr int KC = CIN / 32;
  constexpr int NG = COUT / 16;
  constexpr int NF = COUT / 32;       // n-frags per wave (2 n-waves)
  constexpr int CH8 = CIN / 8;        // 16B chunks per pixel
  constexpr int CH8_LOG = (CH8 == 4) ? 2 : 3;
  constexpr int CHUNKS = 3 * 130 * CH8;
  constexpr int ITERS = (CHUNKS + 255) / 256;

  const int tid = threadIdx.x, lane = tid & 63, wv = tid >> 6;
  const int wave_m = wv >> 1, wave_n = wv & 1;
  const int h = blockIdx.y, b = blockIdx.z, w0 = blockIdx.x * 128;
  const size_t inb = (size_t)b * HWSZ * CIN;

  __shared__ __align__(16) unsigned short lds[3 * 130 * CIN];

  // stage 3 rows x 130 px, BN(scale/shift)+leakyReLU applied on unpack
  #pragma unroll
  for (int i = 0; i < ITERS; ++i) {
    const int c = tid + i * 256;
    if (c < CHUNKS) {
      const int r = c / (130 * CH8);
      const int rem = c - r * (130 * CH8);
      const int px = rem >> CH8_LOG, ck = rem & (CH8 - 1);
      const int hi = h + r - 1, wi = w0 - 1 + px;
      uint4 v = make_uint4(0u, 0u, 0u, 0u);
      if ((unsigned)hi < 256u && (unsigned)wi < 256u) {
        uint4 raw = *(const uint4*)&in[inb + ((size_t)hi * 256 + wi) * CIN + ck * 8];
        const float4 s0 = *(const float4*)&bn_sc[ck * 8];
        const float4 s1 = *(const float4*)&bn_sc[ck * 8 + 4];
        const float4 t0 = *(const float4*)&bn_sh[ck * 8];
        const float4 t1 = *(const float4*)&bn_sh[ck * 8 + 4];
        const float scs[8] = {s0.x, s0.y, s0.z, s0.w, s1.x, s1.y, s1.z, s1.w};
        const float shs[8] = {t0.x, t0.y, t0.z, t0.w, t1.x, t1.y, t1.z, t1.w};
        unsigned int* u = (unsigned int*)&raw;
        unsigned int* o = (unsigned int*)&v;
        #pragma unroll
        for (int p = 0; p < 4; ++p) {
          float a = bf2f((unsigned short)(u[p] & 0xffff));
          float d = bf2f((unsigned short)(u[p] >> 16));
          float ya = a * scs[2 * p] + shs[2 * p];
          float yd = d * scs[2 * p + 1] + shs[2 * p + 1];
          ya = fmaxf(ya, 0.01f * ya);
          yd = fmaxf(yd, 0.01f * yd);
          o[p] = (unsigned int)f2bf(ya) | ((unsigned int)f2bf(yd) << 16);
        }
      }
      *(uint4*)&lds[((size_t)r * 130 + px) * CIN + ((ck ^ (px & (CH8 - 1))) * 8)] = v;
    }
  }
  __syncthreads();

  floatx4 acc[4][NF];
  #pragma unroll
  for (int mf = 0; mf < 4; ++mf)
    #pragma unroll
    for (int nf = 0; nf < NF; ++nf) acc[mf][nf] = (floatx4){0.f, 0.f, 0.f, 0.f};

  const int j15 = lane & 15, q4 = lane >> 4;
  const int base_px = wave_m * 64 + j15;

  #pragma unroll
  for (int dh = 0; dh < 3; ++dh) {
    #pragma unroll
    for (int dw = 0; dw < 3; ++dw) {
      #pragma unroll
      for (int kc = 0; kc < KC; ++kc) {
        short8 a[4];
        #pragma unroll
        for (int mf = 0; mf < 4; ++mf) {
          const int p = dw + base_px + mf * 16;          // px slot 0..129
          const int ck = kc * 4 + q4;
          a[mf] = *(const short8*)&lds[((size_t)dh * 130 + p) * CIN +
                                       ((ck ^ (p & (CH8 - 1))) * 8)];
        }
        const int tap = dh * 3 + dw;
        short8 bg[NF];
        #pragma unroll
        for (int nf = 0; nf < NF; ++nf)
          bg[nf] = *(const short8*)&wf[((((tap * KC + kc) * NG) + wave_n * NF + nf) * 64 + lane) * 8];
        #pragma unroll
        for (int mf = 0; mf < 4; ++mf)
          #pragma unroll
          for (int nf = 0; nf < NF; ++nf)
            acc[mf][nf] = __builtin_amdgcn_mfma_f32_16x16x32_bf16(a[mf], bg[nf], acc[mf][nf], 0, 0, 0);
      }
    }
  }

  // epilogue: +bias, per-wave stats, optional raw bf16 NHWC store
  float sa[NF], qa[NF];
  const size_t orow = ((size_t)(b * 256 + h) * 256 + w0);
  #pragma unroll
  for (int nf = 0; nf < NF; ++nf) {
    const int ch = wave_n * (COUT / 2) + nf * 16 + j15;
    const float bv = bias[ch];
    sa[nf] = 0.f; qa[nf] = 0.f;
    #pragma unroll
    for (int mf = 0; mf < 4; ++mf)
      #pragma unroll
      for (int rr = 0; rr < 4; ++rr) {
        float y = acc[mf][nf][rr] + bv;
        sa[nf] += y; qa[nf] += y * y;
        if constexpr (WRITE_OUT) {
          const int p = wave_m * 64 + mf * 16 + q4 * 4 + rr;
          out[(orow + p) * COUT + ch] = f2bf(y);
        }
      }
  }

  __syncthreads();
  float* red = (float*)lds;  // [4][NF][16] sums, then [4][NF][16] sumsq
  #pragma unroll
  for (int nf = 0; nf < NF; ++nf) {
    float s = sa[nf], q = qa[nf];
    s += __shfl_xor(s, 16); s += __shfl_xor(s, 32);
    q += __shfl_xor(q, 16); q += __shfl_xor(q, 32);
    if (lane < 16) {
      red[(wv * NF + nf) * 16 + lane] = s;
      red[4 * NF * 16 + (wv * NF + nf) * 16 + lane] = q;
    }
  }
  __syncthreads();
  if (tid < COUT) {
    const int wn = tid / (COUT / 2), rr = tid % (COUT / 2);
    const int nf = rr >> 4, li = rr & 15;
    float s = red[(wn * NF + nf) * 16 + li] + red[((wn + 2) * NF + nf) * 16 + li];
    float q = red[4 * NF * 16 + (wn * NF + nf) * 16 + li] +
              red[4 * NF * 16 + ((wn + 2) * NF + nf) * 16 + li];
    const int blk = blockIdx.x + ((int)blockIdx.z * 256 + (int)blockIdx.y) * 2;  // 0..4095
    partial[((size_t)tid * 2 + 0) * NPB2 + blk] = s;
    partial[((size_t)tid * 2 + 1) * NPB2 + blk] = q;
  }
}

// ---- fold partials into scale/shift ---------------------------------------
__global__ __launch_bounds__(256) void reduce_stats(
    const float* __restrict__ partial, const float* __restrict__ gamma,
    const float* __restrict__ beta, float* __restrict__ scale,
    float* __restrict__ shift, int npb)
{
  const int c = blockIdx.x;
  float s = 0.f, q = 0.f;
  for (int i = threadIdx.x; i < npb; i += 256) {
    s += partial[((size_t)c * 2 + 0) * npb + i];
    q += partial[((size_t)c * 2 + 1) * npb + i];
  }
  #pragma unroll
  for (int o = 32; o > 0; o >>= 1) { s += __shfl_down(s, o); q += __shfl_down(q, o); }
  __shared__ float rs[4][2];
  const int lane = threadIdx.x & 63, wv = threadIdx.x >> 6;
  if (lane == 0) { rs[wv][0] = s; rs[wv][1] = q; }
  __syncthreads();
  if (threadIdx.x == 0) {
    s = rs[0][0] + rs[1][0] + rs[2][0] + rs[3][0];
    q = rs[0][1] + rs[1][1] + rs[2][1] + rs[3][1];
    const float N = (float)((size_t)BATCH * HWSZ);
    float mean = s / N;
    float var = q / N - mean * mean;
    float rstd = 1.0f / sqrtf(var + 1e-5f);
    float sc = gamma[c] * rstd;
    scale[c] = sc;
    shift[c] = beta[c] - mean * sc;
  }
}

// ---- fused outputs: patches (blocks 0..13) + encode (blocks 14..17) -------
// encode: conv3 at 8 pixels (n_xy) on RAW y2 (bn2+lrelu on read), bn3 at end.
__global__ __launch_bounds__(256) void outputs_kernel(
    const float* __restrict__ img, const int* __restrict__ axy,
    const int* __restrict__ pxy, const int* __restrict__ nxy,
    const unsigned short* __restrict__ y2, const float* __restrict__ wgt,
    const float* __restrict__ bias,
    const float* __restrict__ sc2, const float* __restrict__ sh2,
    const float* __restrict__ scale, const float* __restrict__ shift,
    float* __restrict__ out)
{
  if (blockIdx.x < 14) {
    const int i = blockIdx.x * 256 + threadIdx.x;
    if (i >= 3 * BATCH * 3 * 49) return;
    const int arr = i / 1176, r = i % 1176;
    const int b = r / 147, q = r % 147;
    const int c = q / 49, s = q % 49;
    const int ph = s / 7, pw = s % 7;
    const int* xy = (arr == 0) ? axy : ((arr == 1) ? pxy : nxy);
    const int x = xy[(b * 32 + 31) * 2 + 0];
    const int y = xy[(b * 32 + 31) * 2 + 1];
    out[i] = img[((size_t)(b * 3 + c) * HH + (x - 3 + ph)) * WW + (y - 3 + pw)];
  } else {
    const int b = (blockIdx.x - 14) * 2 + (threadIdx.x >> 7);
    const int co = threadIdx.x & 127;
    const int x = nxy[(b * 32 + 31) * 2 + 0];
    const int y = nxy[(b * 32 + 31) * 2 + 1];
    float acc = bias[co];
    for (int ci = 0; ci < 64; ++ci) {
      const float s2 = sc2[ci], h2 = sh2[ci];
      #pragma unroll
      for (int dh = -1; dh <= 1; ++dh)
        #pragma unroll
        for (int dw = -1; dw <= 1; ++dw) {
          float v = bf2f(y2[((size_t)(b * 256 + x + dh) * 256 + (y + dw)) * 64 + ci]);
          v = v * s2 + h2;
          v = fmaxf(v, 0.01f * v);
          acc = fmaf(wgt[((size_t)co * 64 + ci) * 9 + (dh + 1) * 3 + (dw + 1)], v, acc);
        }
    }
    const float yv = acc * scale[co] + shift[co];
    out[3528 + b * 128 + co] = fmaxf(yv, 0.01f * yv);
  }
}

extern "C" void kernel_launch(void* const* d_in, const int* in_sizes, int n_in,
                              void* d_out, int out_size, void* d_ws, size_t ws_size,
                              hipStream_t stream)
{
  const float* image = (const float*)d_in[0];
  const int* axy = (const int*)d_in[1];
  const int* pxy = (const int*)d_in[2];
  const int* nxy = (const int*)d_in[3];
  const float* c1w = (const float*)d_in[4];
  const float* c1b = (const float*)d_in[5];
  const float* g1 = (const float*)d_in[6];
  const float* b1 = (const float*)d_in[7];
  const float* c2w = (const float*)d_in[8];
  const float* c2b = (const float*)d_in[9];
  const float* g2 = (const float*)d_in[10];
  const float* b2 = (const float*)d_in[11];
  const float* c3w = (const float*)d_in[12];
  const float* c3b = (const float*)d_in[13];
  const float* g3 = (const float*)d_in[14];
  const float* b3 = (const float*)d_in[15];
  float* out = (float*)d_out;

  // workspace layout (~105 MB)
  unsigned short* zb1 = (unsigned short*)d_ws;            // raw y1, 16.78M bf16
  unsigned short* zb2 = zb1 + (size_t)8 * 32 * HWSZ;      // raw y2, 33.55M bf16
  unsigned short* wf2 = zb2 + (size_t)8 * 64 * HWSZ;      // 18432
  unsigned short* wf3 = wf2 + 18432;                      // 73728
  float* partial = (float*)(wf3 + 73728);                 // 128*2*4096 floats
  float* scale1 = partial + (size_t)128 * 2 * NPB2;
  float* shift1 = scale1 + 32;
  float* scale2 = shift1 + 32;
  float* shift2 = scale2 + 64;
  float* scale3 = shift2 + 64;
  float* shift3 = scale3 + 128;

  prep_all<<<360, 256, 0, stream>>>(c2w, c3w, wf2, wf3);

  // layer 1: 3 -> 32 (VALU fp32, raw bf16 NHWC out + stats)
  conv1_kernel<<<dim3(256, 8), 256, 0, stream>>>(image, c1w, c1b, zb1, partial);
  reduce_stats<<<32, 256, 0, stream>>>(partial, g1, b1, scale1, shift1, 2048);

  // layer 2: 32 -> 64 (MFMA; bn1+lrelu fused in staging; raw y2 out + stats)
  conv_mfma<32, 64, true, 4><<<dim3(2, 256, 8), 256, 0, stream>>>(
      zb1, wf2, c2b, scale1, shift1, zb2, partial);
  reduce_stats<<<64, 256, 0, stream>>>(partial, g2, b2, scale2, shift2, NPB2);

  // layer 3: 64 -> 128 (MFMA; bn2+lrelu fused in staging; stats only)
  conv_mfma<64, 128, false, 3><<<dim3(2, 256, 8), 256, 0, stream>>>(
      zb2, wf3, c3b, scale2, shift2, nullptr, partial);
  reduce_stats<<<128, 256, 0, stream>>>(partial, g3, b3, scale3, shift3, NPB2);

  // outputs: patches + encode fused (bn2 on reads, bn3 at end)
  outputs_kernel<<<18, 256, 0, stream>>>(image, axy, pxy, nxy, zb2, c3w, c3b,
                                         scale2, shift2, scale3, shift3, out);
}

// Round 8
// 315.205 us; speedup vs baseline: 1.6937x; 1.0437x over previous
//
#include <hip/hip_runtime.h>
#include <math.h>

#define HH 256
#define WW 256
#define BATCH 8
#define HWSZ 65536
#define NPB2 4096  // partial slots for conv2/conv3 (4*128*8 blocks)

typedef __attribute__((ext_vector_type(8))) short short8;
typedef __attribute__((ext_vector_type(4))) float floatx4;

__device__ __forceinline__ unsigned short f2bf(float f) {
  union { float f; unsigned int u; } v; v.f = f;
  unsigned int r = v.u + 0x7fff + ((v.u >> 16) & 1);
  return (unsigned short)(r >> 16);
}
__device__ __forceinline__ float bf2f(unsigned short u) {
  union { unsigned int u; float f; } v; v.u = ((unsigned int)u) << 16;
  return v.f;
}

// ---- fused weight pre-swizzle for conv2+conv3: OIHW fp32 -> B-frag bf16 ---
__global__ __launch_bounds__(256) void prep_all(
    const float* __restrict__ w2, const float* __restrict__ w3,
    unsigned short* __restrict__ wf2, unsigned short* __restrict__ wf3)
{
  int idx = blockIdx.x * 256 + threadIdx.x;
  if (idx < 18432) {  // conv2: CIN=32, COUT=64, KC=1, NG=4
    const int j = idx & 7;
    const int lane = (idx >> 3) & 63;
    int rest = idx >> 9;
    const int ng = rest % 4;
    const int tap = rest / 4;
    const int cout = ng * 16 + (lane & 15);
    const int cin = ((lane >> 4) << 3) + j;
    wf2[idx] = f2bf(w2[((size_t)cout * 32 + cin) * 9 + tap]);
  } else {            // conv3: CIN=64, COUT=128, KC=2, NG=8
    idx -= 18432;
    if (idx >= 73728) return;
    const int j = idx & 7;
    const int lane = (idx >> 3) & 63;
    int rest = idx >> 9;
    const int ng = rest % 8; rest /= 8;
    const int kc = rest & 1;
    const int tap = rest >> 1;
    const int cout = ng * 16 + (lane & 15);
    const int cin = kc * 32 + ((lane >> 4) << 3) + j;
    wf3[idx] = f2bf(w3[((size_t)cout * 64 + cin) * 9 + tap]);
  }
}

// ---- conv1: 3->32, fp32 VALU, raw y1 (bias, NO bn) bf16 NHWC direct store -
__global__ __launch_bounds__(256) void conv1_kernel(
    const float* __restrict__ in, const float* __restrict__ wgt,
    const float* __restrict__ bias, unsigned short* __restrict__ out,
    float* __restrict__ partial)
{
  const int w = threadIdx.x, h = blockIdx.x, b = blockIdx.y;
  int off[9]; float msk[9];
  #pragma unroll
  for (int dh = -1; dh <= 1; ++dh)
    #pragma unroll
    for (int dw = -1; dw <= 1; ++dw) {
      int t9 = (dh + 1) * 3 + (dw + 1);
      int hh = h + dh, ww = w + dw;
      bool ok = (hh >= 0) && (hh < HH) && (ww >= 0) && (ww < WW);
      int hc = min(max(hh, 0), HH - 1), wc = min(max(ww, 0), WW - 1);
      off[t9] = hc * WW + wc;
      msk[t9] = ok ? 1.0f : 0.0f;
    }
  const float* inb = in + (size_t)b * 3 * HWSZ;
  float acc[32];
  #pragma unroll
  for (int c = 0; c < 32; ++c) acc[c] = bias[c];
  for (int ci = 0; ci < 3; ++ci) {
    const float* p = inb + (size_t)ci * HWSZ;
    float v[9];
    #pragma unroll
    for (int t = 0; t < 9; ++t) v[t] = p[off[t]] * msk[t];
    #pragma unroll
    for (int c = 0; c < 32; ++c) {
      const float* wr = wgt + ((size_t)c * 3 + ci) * 9;
      #pragma unroll
      for (int t = 0; t < 9; ++t) acc[c] = fmaf(wr[t], v[t], acc[c]);
    }
  }
  __shared__ float red[4][32][2];
  const int lane = threadIdx.x & 63, wv = threadIdx.x >> 6;
  #pragma unroll
  for (int c = 0; c < 32; ++c) {
    float s = acc[c], q = acc[c] * acc[c];
    #pragma unroll
    for (int o = 32; o > 0; o >>= 1) { s += __shfl_down(s, o); q += __shfl_down(q, o); }
    if (lane == 0) { red[wv][c][0] = s; red[wv][c][1] = q; }
  }
  uint4* o4 = (uint4*)(out + ((size_t)((b * 256 + h) * 256 + w)) * 32);
  #pragma unroll
  for (int i = 0; i < 4; ++i) {
    uint4 u;
    u.x = (unsigned int)f2bf(acc[8 * i + 0]) | ((unsigned int)f2bf(acc[8 * i + 1]) << 16);
    u.y = (unsigned int)f2bf(acc[8 * i + 2]) | ((unsigned int)f2bf(acc[8 * i + 3]) << 16);
    u.z = (unsigned int)f2bf(acc[8 * i + 4]) | ((unsigned int)f2bf(acc[8 * i + 5]) << 16);
    u.w = (unsigned int)f2bf(acc[8 * i + 6]) | ((unsigned int)f2bf(acc[8 * i + 7]) << 16);
    o4[i] = u;
  }
  __syncthreads();
  if (threadIdx.x < 64) {
    int c = threadIdx.x >> 1, j = threadIdx.x & 1;
    float r = red[0][c][j] + red[1][c][j] + red[2][c][j] + red[3][c][j];
    int pb = b * 256 + h;
    partial[((size_t)c * 2 + j) * 2048 + pb] = r;
  }
}

// ---- MFMA conv: 64px x 2 ROWS x COUT per block ----------------------------
// RAW input; BN+lrelu fused into staging unpack. Stage 4 rows x 66 px once,
// one barrier, rows interleaved inside the k-step (B loaded once, used by
// both rows). Same 2x2 wave grid, swizzle, and stats reduction as the
// measured-good R4/R7 kernel. MINW=2: no register squeeze (spill canary:
// WRITE_SIZE must stay ~output-only).
template<int CIN, int COUT, bool WRITE_OUT, int MINW>
__global__ __launch_bounds__(256, MINW) void conv_mfma(
    const unsigned short* __restrict__ in, const unsigned short* __restrict__ wf,
    const float* __restrict__ bias,
    const float* __restrict__ bn_sc, const float* __restrict__ bn_sh,
    unsigned short* __restrict__ out, float* __restrict__ partial)
{
  constexpr int KC = CIN / 32;
  constexpr int NG = COUT / 16;
  constexpr int NF = COUT / 32;       // n-frags per wave (2 n-waves)
  constexpr int CH8 = CIN / 8;        // 16B chunks per pixel
  constexpr int CH8_LOG = (CH8 == 4) ? 2 : 3;
  constexpr int ROWSZ = 66 * CIN;     // halfwords per LDS row
  constexpr int CHUNKS = 4 * 66 * CH8;
  constexpr int ITERS = (CHUNKS + 255) / 256;

  const int tid = threadIdx.x, lane = tid & 63, wv = tid >> 6;
  const int wave_m = wv >> 1, wave_n = wv & 1;
  const int h0 = blockIdx.y * 2, b = blockIdx.z, w0 = blockIdx.x * 64;
  const size_t inb = (size_t)b * HWSZ * CIN;

  __shared__ __align__(16) unsigned short lds[4 * 66 * CIN];

  // stage 4 rows x 66 px, BN(scale/shift)+leakyReLU applied on unpack
  #pragma unroll
  for (int i = 0; i < ITERS; ++i) {
    const int c = tid + i * 256;
    if (c < CHUNKS) {
      const int r = c / (66 * CH8);
      const int rem = c - r * (66 * CH8);
      const int px = rem >> CH8_LOG, ck = rem & (CH8 - 1);
      const int hi = h0 + r - 1, wi = w0 - 1 + px;
      uint4 v = make_uint4(0u, 0u, 0u, 0u);
      if ((unsigned)hi < 256u && (unsigned)wi < 256u) {
        uint4 raw = *(const uint4*)&in[inb + ((size_t)hi * 256 + wi) * CIN + ck * 8];
        const float4 s0 = *(const float4*)&bn_sc[ck * 8];
        const float4 s1 = *(const float4*)&bn_sc[ck * 8 + 4];
        const float4 t0 = *(const float4*)&bn_sh[ck * 8];
        const float4 t1 = *(const float4*)&bn_sh[ck * 8 + 4];
        const float scs[8] = {s0.x, s0.y, s0.z, s0.w, s1.x, s1.y, s1.z, s1.w};
        const float shs[8] = {t0.x, t0.y, t0.z, t0.w, t1.x, t1.y, t1.z, t1.w};
        unsigned int* u = (unsigned int*)&raw;
        unsigned int* o = (unsigned int*)&v;
        #pragma unroll
        for (int p = 0; p < 4; ++p) {
          float a = bf2f((unsigned short)(u[p] & 0xffff));
          float d = bf2f((unsigned short)(u[p] >> 16));
          float ya = a * scs[2 * p] + shs[2 * p];
          float yd = d * scs[2 * p + 1] + shs[2 * p + 1];
          ya = fmaxf(ya, 0.01f * ya);
          yd = fmaxf(yd, 0.01f * yd);
          o[p] = (unsigned int)f2bf(ya) | ((unsigned int)f2bf(yd) << 16);
        }
      }
      *(uint4*)&lds[((size_t)r * 66 + px) * CIN + ((ck ^ (px & (CH8 - 1))) * 8)] = v;
    }
  }
  __syncthreads();

  const int j15 = lane & 15, q4 = lane >> 4;
  const int base_px = wave_m * 32 + j15;

  floatx4 acc[2][2][NF];  // [row][mf][nf]
  #pragma unroll
  for (int rr = 0; rr < 2; ++rr)
    #pragma unroll
    for (int mf = 0; mf < 2; ++mf)
      #pragma unroll
      for (int nf = 0; nf < NF; ++nf) acc[rr][mf][nf] = (floatx4){0.f, 0.f, 0.f, 0.f};

  #pragma unroll
  for (int dh = 0; dh < 3; ++dh) {
    #pragma unroll
    for (int dw = 0; dw < 3; ++dw) {
      #pragma unroll
      for (int kc = 0; kc < KC; ++kc) {
        const int tap = dh * 3 + dw;
        short8 bg[NF];
        #pragma unroll
        for (int nf = 0; nf < NF; ++nf)
          bg[nf] = *(const short8*)&wf[((((tap * KC + kc) * NG) + wave_n * NF + nf) * 64 + lane) * 8];
        #pragma unroll
        for (int rr = 0; rr < 2; ++rr) {
          short8 a[2];
          #pragma unroll
          for (int mf = 0; mf < 2; ++mf) {
            const int p = dw + base_px + mf * 16;        // px slot 0..65
            const int ck = kc * 4 + q4;
            a[mf] = *(const short8*)&lds[((size_t)(rr + dh) * 66 + p) * CIN +
                                         ((ck ^ (p & (CH8 - 1))) * 8)];
          }
          #pragma unroll
          for (int mf = 0; mf < 2; ++mf)
            #pragma unroll
            for (int nf = 0; nf < NF; ++nf)
              acc[rr][mf][nf] = __builtin_amdgcn_mfma_f32_16x16x32_bf16(a[mf], bg[nf], acc[rr][mf][nf], 0, 0, 0);
        }
      }
    }
  }

  // epilogue: +bias, per-wave stats over both rows, optional bf16 NHWC store
  float bv[NF], sa[NF], qa[NF];
  #pragma unroll
  for (int nf = 0; nf < NF; ++nf) {
    bv[nf] = bias[wave_n * (COUT / 2) + nf * 16 + j15];
    sa[nf] = 0.f; qa[nf] = 0.f;
  }
  #pragma unroll
  for (int rr = 0; rr < 2; ++rr) {
    const size_t orow = ((size_t)(b * 256 + (h0 + rr)) * 256 + w0);
    #pragma unroll
    for (int nf = 0; nf < NF; ++nf) {
      const int ch = wave_n * (COUT / 2) + nf * 16 + j15;
      #pragma unroll
      for (int mf = 0; mf < 2; ++mf)
        #pragma unroll
        for (int r4 = 0; r4 < 4; ++r4) {
          float y = acc[rr][mf][nf][r4] + bv[nf];
          sa[nf] += y; qa[nf] += y * y;
          if constexpr (WRITE_OUT) {
            const int p = wave_m * 32 + mf * 16 + q4 * 4 + r4;
            out[(orow + p) * COUT + ch] = f2bf(y);
          }
        }
    }
  }

  __syncthreads();
  float* red = (float*)lds;  // [4][NF][16] sums, then [4][NF][16] sumsq
  #pragma unroll
  for (int nf = 0; nf < NF; ++nf) {
    float s = sa[nf], q = qa[nf];
    s += __shfl_xor(s, 16); s += __shfl_xor(s, 32);
    q += __shfl_xor(q, 16); q += __shfl_xor(q, 32);
    if (lane < 16) {
      red[(wv * NF + nf) * 16 + lane] = s;
      red[4 * NF * 16 + (wv * NF + nf) * 16 + lane] = q;
    }
  }
  __syncthreads();
  if (tid < COUT) {
    const int wn = tid / (COUT / 2), rr = tid % (COUT / 2);
    const int nf = rr >> 4, li = rr & 15;
    float s = red[(wn * NF + nf) * 16 + li] + red[((wn + 2) * NF + nf) * 16 + li];
    float q = red[4 * NF * 16 + (wn * NF + nf) * 16 + li] +
              red[4 * NF * 16 + ((wn + 2) * NF + nf) * 16 + li];
    const int blk = blockIdx.x + ((int)blockIdx.z * 128 + (int)blockIdx.y) * 4;  // 0..4095
    partial[((size_t)tid * 2 + 0) * NPB2 + blk] = s;
    partial[((size_t)tid * 2 + 1) * NPB2 + blk] = q;
  }
}

// ---- fold partials into scale/shift ---------------------------------------
__global__ __launch_bounds__(256) void reduce_stats(
    const float* __restrict__ partial, const float* __restrict__ gamma,
    const float* __restrict__ beta, float* __restrict__ scale,
    float* __restrict__ shift, int npb)
{
  const int c = blockIdx.x;
  float s = 0.f, q = 0.f;
  for (int i = threadIdx.x; i < npb; i += 256) {
    s += partial[((size_t)c * 2 + 0) * npb + i];
    q += partial[((size_t)c * 2 + 1) * npb + i];
  }
  #pragma unroll
  for (int o = 32; o > 0; o >>= 1) { s += __shfl_down(s, o); q += __shfl_down(q, o); }
  __shared__ float rs[4][2];
  const int lane = threadIdx.x & 63, wv = threadIdx.x >> 6;
  if (lane == 0) { rs[wv][0] = s; rs[wv][1] = q; }
  __syncthreads();
  if (threadIdx.x == 0) {
    s = rs[0][0] + rs[1][0] + rs[2][0] + rs[3][0];
    q = rs[0][1] + rs[1][1] + rs[2][1] + rs[3][1];
    const float N = (float)((size_t)BATCH * HWSZ);
    float mean = s / N;
    float var = q / N - mean * mean;
    float rstd = 1.0f / sqrtf(var + 1e-5f);
    float sc = gamma[c] * rstd;
    scale[c] = sc;
    shift[c] = beta[c] - mean * sc;
  }
}

// ---- fused outputs: patches (blocks 0..13) + encode (blocks 14..17) -------
// encode: conv3 at 8 pixels (n_xy) on RAW y2 (bn2+lrelu on read), bn3 at end.
__global__ __launch_bounds__(256) void outputs_kernel(
    const float* __restrict__ img, const int* __restrict__ axy,
    const int* __restrict__ pxy, const int* __restrict__ nxy,
    const unsigned short* __restrict__ y2, const float* __restrict__ wgt,
    const float* __restrict__ bias,
    const float* __restrict__ sc2, const float* __restrict__ sh2,
    const float* __restrict__ scale, const float* __restrict__ shift,
    float* __restrict__ out)
{
  if (blockIdx.x < 14) {
    const int i = blockIdx.x * 256 + threadIdx.x;
    if (i >= 3 * BATCH * 3 * 49) return;
    const int arr = i / 1176, r = i % 1176;
    const int b = r / 147, q = r % 147;
    const int c = q / 49, s = q % 49;
    const int ph = s / 7, pw = s % 7;
    const int* xy = (arr == 0) ? axy : ((arr == 1) ? pxy : nxy);
    const int x = xy[(b * 32 + 31) * 2 + 0];
    const int y = xy[(b * 32 + 31) * 2 + 1];
    out[i] = img[((size_t)(b * 3 + c) * HH + (x - 3 + ph)) * WW + (y - 3 + pw)];
  } else {
    const int b = (blockIdx.x - 14) * 2 + (threadIdx.x >> 7);
    const int co = threadIdx.x & 127;
    const int x = nxy[(b * 32 + 31) * 2 + 0];
    const int y = nxy[(b * 32 + 31) * 2 + 1];
    float acc = bias[co];
    for (int ci = 0; ci < 64; ++ci) {
      const float s2 = sc2[ci], h2 = sh2[ci];
      #pragma unroll
      for (int dh = -1; dh <= 1; ++dh)
        #pragma unroll
        for (int dw = -1; dw <= 1; ++dw) {
          float v = bf2f(y2[((size_t)(b * 256 + x + dh) * 256 + (y + dw)) * 64 + ci]);
          v = v * s2 + h2;
          v = fmaxf(v, 0.01f * v);
          acc = fmaf(wgt[((size_t)co * 64 + ci) * 9 + (dh + 1) * 3 + (dw + 1)], v, acc);
        }
    }
    const float yv = acc * scale[co] + shift[co];
    out[3528 + b * 128 + co] = fmaxf(yv, 0.01f * yv);
  }
}

extern "C" void kernel_launch(void* const* d_in, const int* in_sizes, int n_in,
                              void* d_out, int out_size, void* d_ws, size_t ws_size,
                              hipStream_t stream)
{
  const float* image = (const float*)d_in[0];
  const int* axy = (const int*)d_in[1];
  const int* pxy = (const int*)d_in[2];
  const int* nxy = (const int*)d_in[3];
  const float* c1w = (const float*)d_in[4];
  const float* c1b = (const float*)d_in[5];
  const float* g1 = (const float*)d_in[6];
  const float* b1 = (const float*)d_in[7];
  const float* c2w = (const float*)d_in[8];
  const float* c2b = (const float*)d_in[9];
  const float* g2 = (const float*)d_in[10];
  const float* b2 = (const float*)d_in[11];
  const float* c3w = (const float*)d_in[12];
  const float* c3b = (const float*)d_in[13];
  const float* g3 = (const float*)d_in[14];
  const float* b3 = (const float*)d_in[15];
  float* out = (float*)d_out;

  // workspace layout (~105 MB)
  unsigned short* zb1 = (unsigned short*)d_ws;            // raw y1, 16.78M bf16
  unsigned short* zb2 = zb1 + (size_t)8 * 32 * HWSZ;      // raw y2, 33.55M bf16
  unsigned short* wf2 = zb2 + (size_t)8 * 64 * HWSZ;      // 18432
  unsigned short* wf3 = wf2 + 18432;                      // 73728
  float* partial = (float*)(wf3 + 73728);                 // 128*2*4096 floats
  float* scale1 = partial + (size_t)128 * 2 * NPB2;
  float* shift1 = scale1 + 32;
  float* scale2 = shift1 + 32;
  float* shift2 = scale2 + 64;
  float* scale3 = shift2 + 64;
  float* shift3 = scale3 + 128;

  prep_all<<<360, 256, 0, stream>>>(c2w, c3w, wf2, wf3);

  // layer 1: 3 -> 32 (VALU fp32, raw bf16 NHWC out + stats)
  conv1_kernel<<<dim3(256, 8), 256, 0, stream>>>(image, c1w, c1b, zb1, partial);
  reduce_stats<<<32, 256, 0, stream>>>(partial, g1, b1, scale1, shift1, 2048);

  // layer 2: 32 -> 64 (MFMA; bn1+lrelu fused in staging; raw y2 out + stats)
  conv_mfma<32, 64, true, 2><<<dim3(4, 128, 8), 256, 0, stream>>>(
      zb1, wf2, c2b, scale1, shift1, zb2, partial);
  reduce_stats<<<64, 256, 0, stream>>>(partial, g2, b2, scale2, shift2, NPB2);

  // layer 3: 64 -> 128 (MFMA; bn2+lrelu fused in staging; stats only)
  conv_mfma<64, 128, false, 2><<<dim3(4, 128, 8), 256, 0, stream>>>(
      zb2, wf3, c3b, scale2, shift2, nullptr, partial);
  reduce_stats<<<128, 256, 0, stream>>>(partial, g3, b3, scale3, shift3, NPB2);

  // outputs: patches + encode fused (bn2 on reads, bn3 at end)
  outputs_kernel<<<18, 256, 0, stream>>>(image, axy, pxy, nxy, zb2, c3w, c3b,
                                         scale2, shift2, scale3, shift3, out);
}

// Round 9
// 311.976 us; speedup vs baseline: 1.7112x; 1.0104x over previous
//
#include <hip/hip_runtime.h>
#include <math.h>

#define HH 256
#define WW 256
#define BATCH 8
#define HWSZ 65536
#define NPB2 4096  // partial slots for conv2/conv3 (4*128*8 blocks)

typedef __attribute__((ext_vector_type(8))) short short8;
typedef __attribute__((ext_vector_type(4))) float floatx4;

// round-half-up bf16 pack: 2 VALU ops, max err 0.5 ulp (vs 4-op RNE)
__device__ __forceinline__ unsigned short f2bf(float f) {
  union { float f; unsigned int u; } v; v.f = f;
  return (unsigned short)((v.u + 0x8000u) >> 16);
}
// pack two fp32 -> bf16x2 (lo=a, hi=d): 5 VALU ops
__device__ __forceinline__ unsigned int pack2bf(float a, float d) {
  union { float f; unsigned int u; } va, vd; va.f = a; vd.f = d;
  return ((va.u + 0x8000u) >> 16) | ((vd.u + 0x8000u) & 0xffff0000u);
}
__device__ __forceinline__ float bf2f(unsigned short u) {
  union { unsigned int u; float f; } v; v.u = ((unsigned int)u) << 16;
  return v.f;
}

// ---- fused weight pre-swizzle for conv2+conv3: OIHW fp32 -> B-frag bf16 ---
__global__ __launch_bounds__(256) void prep_all(
    const float* __restrict__ w2, const float* __restrict__ w3,
    unsigned short* __restrict__ wf2, unsigned short* __restrict__ wf3)
{
  int idx = blockIdx.x * 256 + threadIdx.x;
  if (idx < 18432) {  // conv2: CIN=32, COUT=64, KC=1, NG=4
    const int j = idx & 7;
    const int lane = (idx >> 3) & 63;
    int rest = idx >> 9;
    const int ng = rest % 4;
    const int tap = rest / 4;
    const int cout = ng * 16 + (lane & 15);
    const int cin = ((lane >> 4) << 3) + j;
    wf2[idx] = f2bf(w2[((size_t)cout * 32 + cin) * 9 + tap]);
  } else {            // conv3: CIN=64, COUT=128, KC=2, NG=8
    idx -= 18432;
    if (idx >= 73728) return;
    const int j = idx & 7;
    const int lane = (idx >> 3) & 63;
    int rest = idx >> 9;
    const int ng = rest % 8; rest /= 8;
    const int kc = rest & 1;
    const int tap = rest >> 1;
    const int cout = ng * 16 + (lane & 15);
    const int cin = kc * 32 + ((lane >> 4) << 3) + j;
    wf3[idx] = f2bf(w3[((size_t)cout * 64 + cin) * 9 + tap]);
  }
}

// ---- conv1: 3->32, fp32 VALU, raw y1 (bias, NO bn) bf16 NHWC direct store -
__global__ __launch_bounds__(256) void conv1_kernel(
    const float* __restrict__ in, const float* __restrict__ wgt,
    const float* __restrict__ bias, unsigned short* __restrict__ out,
    float* __restrict__ partial)
{
  const int w = threadIdx.x, h = blockIdx.x, b = blockIdx.y;
  int off[9]; float msk[9];
  #pragma unroll
  for (int dh = -1; dh <= 1; ++dh)
    #pragma unroll
    for (int dw = -1; dw <= 1; ++dw) {
      int t9 = (dh + 1) * 3 + (dw + 1);
      int hh = h + dh, ww = w + dw;
      bool ok = (hh >= 0) && (hh < HH) && (ww >= 0) && (ww < WW);
      int hc = min(max(hh, 0), HH - 1), wc = min(max(ww, 0), WW - 1);
      off[t9] = hc * WW + wc;
      msk[t9] = ok ? 1.0f : 0.0f;
    }
  const float* inb = in + (size_t)b * 3 * HWSZ;
  float acc[32];
  #pragma unroll
  for (int c = 0; c < 32; ++c) acc[c] = bias[c];
  for (int ci = 0; ci < 3; ++ci) {
    const float* p = inb + (size_t)ci * HWSZ;
    float v[9];
    #pragma unroll
    for (int t = 0; t < 9; ++t) v[t] = p[off[t]] * msk[t];
    #pragma unroll
    for (int c = 0; c < 32; ++c) {
      const float* wr = wgt + ((size_t)c * 3 + ci) * 9;
      #pragma unroll
      for (int t = 0; t < 9; ++t) acc[c] = fmaf(wr[t], v[t], acc[c]);
    }
  }
  __shared__ float red[4][32][2];
  const int lane = threadIdx.x & 63, wv = threadIdx.x >> 6;
  #pragma unroll
  for (int c = 0; c < 32; ++c) {
    float s = acc[c], q = acc[c] * acc[c];
    #pragma unroll
    for (int o = 32; o > 0; o >>= 1) { s += __shfl_down(s, o); q += __shfl_down(q, o); }
    if (lane == 0) { red[wv][c][0] = s; red[wv][c][1] = q; }
  }
  uint4* o4 = (uint4*)(out + ((size_t)((b * 256 + h) * 256 + w)) * 32);
  #pragma unroll
  for (int i = 0; i < 4; ++i) {
    uint4 u;
    u.x = pack2bf(acc[8 * i + 0], acc[8 * i + 1]);
    u.y = pack2bf(acc[8 * i + 2], acc[8 * i + 3]);
    u.z = pack2bf(acc[8 * i + 4], acc[8 * i + 5]);
    u.w = pack2bf(acc[8 * i + 6], acc[8 * i + 7]);
    o4[i] = u;
  }
  __syncthreads();
  if (threadIdx.x < 64) {
    int c = threadIdx.x >> 1, j = threadIdx.x & 1;
    float r = red[0][c][j] + red[1][c][j] + red[2][c][j] + red[3][c][j];
    int pb = b * 256 + h;
    partial[((size_t)c * 2 + j) * 2048 + pb] = r;
  }
}

// ---- MFMA conv: 64px x 2 ROWS x COUT per block ----------------------------
// RAW input; BN+lrelu fused into staging unpack (cheap half-up pack). Stage
// 4 rows x 66 px once, one barrier, rows interleaved inside the k-step
// (B loaded once, used by both rows). Runtime strided staging loop (the
// compile-time unroll measured +8.5us on conv3 in R7 -- do not reinstate).
template<int CIN, int COUT, bool WRITE_OUT, int MINW>
__global__ __launch_bounds__(256, MINW) void conv_mfma(
    const unsigned short* __restrict__ in, const unsigned short* __restrict__ wf,
    const float* __restrict__ bias,
    const float* __restrict__ bn_sc, const float* __restrict__ bn_sh,
    unsigned short* __restrict__ out, float* __restrict__ partial)
{
  constexpr int KC = CIN / 32;
  constexpr int NG = COUT / 16;
  constexpr int NF = COUT / 32;       // n-frags per wave (2 n-waves)
  constexpr int CH8 = CIN / 8;        // 16B chunks per pixel
  constexpr int CH8_LOG = (CH8 == 4) ? 2 : 3;
  constexpr int CHUNKS = 4 * 66 * CH8;

  const int tid = threadIdx.x, lane = tid & 63, wv = tid >> 6;
  const int wave_m = wv >> 1, wave_n = wv & 1;
  const int h0 = blockIdx.y * 2, b = blockIdx.z, w0 = blockIdx.x * 64;
  const size_t inb = (size_t)b * HWSZ * CIN;

  __shared__ __align__(16) unsigned short lds[4 * 66 * CIN];

  // stage 4 rows x 66 px, BN(scale/shift)+leakyReLU applied on unpack
  for (int c = tid; c < CHUNKS; c += 256) {
    const int r = c / (66 * CH8);
    const int rem = c - r * (66 * CH8);
    const int px = rem >> CH8_LOG, ck = rem & (CH8 - 1);
    const int hi = h0 + r - 1, wi = w0 - 1 + px;
    uint4 v = make_uint4(0u, 0u, 0u, 0u);
    if ((unsigned)hi < 256u && (unsigned)wi < 256u) {
      uint4 raw = *(const uint4*)&in[inb + ((size_t)hi * 256 + wi) * CIN + ck * 8];
      const float4 s0 = *(const float4*)&bn_sc[ck * 8];
      const float4 s1 = *(const float4*)&bn_sc[ck * 8 + 4];
      const float4 t0 = *(const float4*)&bn_sh[ck * 8];
      const float4 t1 = *(const float4*)&bn_sh[ck * 8 + 4];
      const float scs[8] = {s0.x, s0.y, s0.z, s0.w, s1.x, s1.y, s1.z, s1.w};
      const float shs[8] = {t0.x, t0.y, t0.z, t0.w, t1.x, t1.y, t1.z, t1.w};
      unsigned int* u = (unsigned int*)&raw;
      unsigned int* o = (unsigned int*)&v;
      #pragma unroll
      for (int p = 0; p < 4; ++p) {
        float a = bf2f((unsigned short)(u[p] & 0xffff));
        float d = bf2f((unsigned short)(u[p] >> 16));
        float ya = a * scs[2 * p] + shs[2 * p];
        float yd = d * scs[2 * p + 1] + shs[2 * p + 1];
        ya = fmaxf(ya, 0.01f * ya);
        yd = fmaxf(yd, 0.01f * yd);
        o[p] = pack2bf(ya, yd);
      }
    }
    *(uint4*)&lds[((size_t)r * 66 + px) * CIN + ((ck ^ (px & (CH8 - 1))) * 8)] = v;
  }
  __syncthreads();

  const int j15 = lane & 15, q4 = lane >> 4;
  const int base_px = wave_m * 32 + j15;

  floatx4 acc[2][2][NF];  // [row][mf][nf]
  #pragma unroll
  for (int rr = 0; rr < 2; ++rr)
    #pragma unroll
    for (int mf = 0; mf < 2; ++mf)
      #pragma unroll
      for (int nf = 0; nf < NF; ++nf) acc[rr][mf][nf] = (floatx4){0.f, 0.f, 0.f, 0.f};

  #pragma unroll
  for (int dh = 0; dh < 3; ++dh) {
    #pragma unroll
    for (int dw = 0; dw < 3; ++dw) {
      #pragma unroll
      for (int kc = 0; kc < KC; ++kc) {
        const int tap = dh * 3 + dw;
        short8 bg[NF];
        #pragma unroll
        for (int nf = 0; nf < NF; ++nf)
          bg[nf] = *(const short8*)&wf[((((tap * KC + kc) * NG) + wave_n * NF + nf) * 64 + lane) * 8];
        #pragma unroll
        for (int rr = 0; rr < 2; ++rr) {
          short8 a[2];
          #pragma unroll
          for (int mf = 0; mf < 2; ++mf) {
            const int p = dw + base_px + mf * 16;        // px slot 0..65
            const int ck = kc * 4 + q4;
            a[mf] = *(const short8*)&lds[((size_t)(rr + dh) * 66 + p) * CIN +
                                         ((ck ^ (p & (CH8 - 1))) * 8)];
          }
          #pragma unroll
          for (int mf = 0; mf < 2; ++mf)
            #pragma unroll
            for (int nf = 0; nf < NF; ++nf)
              acc[rr][mf][nf] = __builtin_amdgcn_mfma_f32_16x16x32_bf16(a[mf], bg[nf], acc[rr][mf][nf], 0, 0, 0);
        }
      }
    }
  }

  // epilogue: +bias, per-wave stats over both rows, optional bf16 NHWC store
  float bv[NF], sa[NF], qa[NF];
  #pragma unroll
  for (int nf = 0; nf < NF; ++nf) {
    bv[nf] = bias[wave_n * (COUT / 2) + nf * 16 + j15];
    sa[nf] = 0.f; qa[nf] = 0.f;
  }
  #pragma unroll
  for (int rr = 0; rr < 2; ++rr) {
    const size_t orow = ((size_t)(b * 256 + (h0 + rr)) * 256 + w0);
    #pragma unroll
    for (int nf = 0; nf < NF; ++nf) {
      const int ch = wave_n * (COUT / 2) + nf * 16 + j15;
      #pragma unroll
      for (int mf = 0; mf < 2; ++mf)
        #pragma unroll
        for (int r4 = 0; r4 < 4; ++r4) {
          float y = acc[rr][mf][nf][r4] + bv[nf];
          sa[nf] += y; qa[nf] += y * y;
          if constexpr (WRITE_OUT) {
            const int p = wave_m * 32 + mf * 16 + q4 * 4 + r4;
            out[(orow + p) * COUT + ch] = f2bf(y);
          }
        }
    }
  }

  __syncthreads();
  float* red = (float*)lds;  // [4][NF][16] sums, then [4][NF][16] sumsq
  #pragma unroll
  for (int nf = 0; nf < NF; ++nf) {
    float s = sa[nf], q = qa[nf];
    s += __shfl_xor(s, 16); s += __shfl_xor(s, 32);
    q += __shfl_xor(q, 16); q += __shfl_xor(q, 32);
    if (lane < 16) {
      red[(wv * NF + nf) * 16 + lane] = s;
      red[4 * NF * 16 + (wv * NF + nf) * 16 + lane] = q;
    }
  }
  __syncthreads();
  if (tid < COUT) {
    const int wn = tid / (COUT / 2), rr = tid % (COUT / 2);
    const int nf = rr >> 4, li = rr & 15;
    float s = red[(wn * NF + nf) * 16 + li] + red[((wn + 2) * NF + nf) * 16 + li];
    float q = red[4 * NF * 16 + (wn * NF + nf) * 16 + li] +
              red[4 * NF * 16 + ((wn + 2) * NF + nf) * 16 + li];
    const int blk = blockIdx.x + ((int)blockIdx.z * 128 + (int)blockIdx.y) * 4;  // 0..4095
    partial[((size_t)tid * 2 + 0) * NPB2 + blk] = s;
    partial[((size_t)tid * 2 + 1) * NPB2 + blk] = q;
  }
}

// ---- fold partials into scale/shift ---------------------------------------
__global__ __launch_bounds__(256) void reduce_stats(
    const float* __restrict__ partial, const float* __restrict__ gamma,
    const float* __restrict__ beta, float* __restrict__ scale,
    float* __restrict__ shift, int npb)
{
  const int c = blockIdx.x;
  float s = 0.f, q = 0.f;
  for (int i = threadIdx.x; i < npb; i += 256) {
    s += partial[((size_t)c * 2 + 0) * npb + i];
    q += partial[((size_t)c * 2 + 1) * npb + i];
  }
  #pragma unroll
  for (int o = 32; o > 0; o >>= 1) { s += __shfl_down(s, o); q += __shfl_down(q, o); }
  __shared__ float rs[4][2];
  const int lane = threadIdx.x & 63, wv = threadIdx.x >> 6;
  if (lane == 0) { rs[wv][0] = s; rs[wv][1] = q; }
  __syncthreads();
  if (threadIdx.x == 0) {
    s = rs[0][0] + rs[1][0] + rs[2][0] + rs[3][0];
    q = rs[0][1] + rs[1][1] + rs[2][1] + rs[3][1];
    const float N = (float)((size_t)BATCH * HWSZ);
    float mean = s / N;
    float var = q / N - mean * mean;
    float rstd = 1.0f / sqrtf(var + 1e-5f);
    float sc = gamma[c] * rstd;
    scale[c] = sc;
    shift[c] = beta[c] - mean * sc;
  }
}

// ---- fused outputs: patches (blocks 0..13) + encode (blocks 14..17) -------
// encode: conv3 at 8 pixels (n_xy) on RAW y2 (bn2+lrelu on read), bn3 at end.
__global__ __launch_bounds__(256) void outputs_kernel(
    const float* __restrict__ img, const int* __restrict__ axy,
    const int* __restrict__ pxy, const int* __restrict__ nxy,
    const unsigned short* __restrict__ y2, const float* __restrict__ wgt,
    const float* __restrict__ bias,
    const float* __restrict__ sc2, const float* __restrict__ sh2,
    const float* __restrict__ scale, const float* __restrict__ shift,
    float* __restrict__ out)
{
  if (blockIdx.x < 14) {
    const int i = blockIdx.x * 256 + threadIdx.x;
    if (i >= 3 * BATCH * 3 * 49) return;
    const int arr = i / 1176, r = i % 1176;
    const int b = r / 147, q = r % 147;
    const int c = q / 49, s = q % 49;
    const int ph = s / 7, pw = s % 7;
    const int* xy = (arr == 0) ? axy : ((arr == 1) ? pxy : nxy);
    const int x = xy[(b * 32 + 31) * 2 + 0];
    const int y = xy[(b * 32 + 31) * 2 + 1];
    out[i] = img[((size_t)(b * 3 + c) * HH + (x - 3 + ph)) * WW + (y - 3 + pw)];
  } else {
    const int b = (blockIdx.x - 14) * 2 + (threadIdx.x >> 7);
    const int co = threadIdx.x & 127;
    const int x = nxy[(b * 32 + 31) * 2 + 0];
    const int y = nxy[(b * 32 + 31) * 2 + 1];
    float acc = bias[co];
    for (int ci = 0; ci < 64; ++ci) {
      const float s2 = sc2[ci], h2 = sh2[ci];
      #pragma unroll
      for (int dh = -1; dh <= 1; ++dh)
        #pragma unroll
        for (int dw = -1; dw <= 1; ++dw) {
          float v = bf2f(y2[((size_t)(b * 256 + x + dh) * 256 + (y + dw)) * 64 + ci]);
          v = v * s2 + h2;
          v = fmaxf(v, 0.01f * v);
          acc = fmaf(wgt[((size_t)co * 64 + ci) * 9 + (dh + 1) * 3 + (dw + 1)], v, acc);
        }
    }
    const float yv = acc * scale[co] + shift[co];
    out[3528 + b * 128 + co] = fmaxf(yv, 0.01f * yv);
  }
}

extern "C" void kernel_launch(void* const* d_in, const int* in_sizes, int n_in,
                              void* d_out, int out_size, void* d_ws, size_t ws_size,
                              hipStream_t stream)
{
  const float* image = (const float*)d_in[0];
  const int* axy = (const int*)d_in[1];
  const int* pxy = (const int*)d_in[2];
  const int* nxy = (const int*)d_in[3];
  const float* c1w = (const float*)d_in[4];
  const float* c1b = (const float*)d_in[5];
  const float* g1 = (const float*)d_in[6];
  const float* b1 = (const float*)d_in[7];
  const float* c2w = (const float*)d_in[8];
  const float* c2b = (const float*)d_in[9];
  const float* g2 = (const float*)d_in[10];
  const float* b2 = (const float*)d_in[11];
  const float* c3w = (const float*)d_in[12];
  const float* c3b = (const float*)d_in[13];
  const float* g3 = (const float*)d_in[14];
  const float* b3 = (const float*)d_in[15];
  float* out = (float*)d_out;

  // workspace layout (~105 MB)
  unsigned short* zb1 = (unsigned short*)d_ws;            // raw y1, 16.78M bf16
  unsigned short* zb2 = zb1 + (size_t)8 * 32 * HWSZ;      // raw y2, 33.55M bf16
  unsigned short* wf2 = zb2 + (size_t)8 * 64 * HWSZ;      // 18432
  unsigned short* wf3 = wf2 + 18432;                      // 73728
  float* partial = (float*)(wf3 + 73728);                 // 128*2*4096 floats
  float* scale1 = partial + (size_t)128 * 2 * NPB2;
  float* shift1 = scale1 + 32;
  float* scale2 = shift1 + 32;
  float* shift2 = scale2 + 64;
  float* scale3 = shift2 + 64;
  float* shift3 = scale3 + 128;

  prep_all<<<360, 256, 0, stream>>>(c2w, c3w, wf2, wf3);

  // layer 1: 3 -> 32 (VALU fp32, raw bf16 NHWC out + stats)
  conv1_kernel<<<dim3(256, 8), 256, 0, stream>>>(image, c1w, c1b, zb1, partial);
  reduce_stats<<<32, 256, 0, stream>>>(partial, g1, b1, scale1, shift1, 2048);

  // layer 2: 32 -> 64 (MFMA; bn1+lrelu fused in staging; raw y2 out + stats)
  conv_mfma<32, 64, true, 2><<<dim3(4, 128, 8), 256, 0, stream>>>(
      zb1, wf2, c2b, scale1, shift1, zb2, partial);
  reduce_stats<<<64, 256, 0, stream>>>(partial, g2, b2, scale2, shift2, NPB2);

  // layer 3: 64 -> 128 (MFMA; bn2+lrelu fused in staging; stats only)
  conv_mfma<64, 128, false, 2><<<dim3(4, 128, 8), 256, 0, stream>>>(
      zb2, wf3, c3b, scale2, shift2, nullptr, partial);
  reduce_stats<<<128, 256, 0, stream>>>(partial, g3, b3, scale3, shift3, NPB2);

  // outputs: patches + encode fused (bn2 on reads, bn3 at end)
  outputs_kernel<<<18, 256, 0, stream>>>(image, axy, pxy, nxy, zb2, c3w, c3b,
                                         scale2, shift2, scale3, shift3, out);
}

// Round 10
// 308.385 us; speedup vs baseline: 1.7311x; 1.0116x over previous
//
#include <hip/hip_runtime.h>
#include <math.h>

#define HH 256
#define WW 256
#define BATCH 8
#define HWSZ 65536
#define NPB2 4096  // partial slots for conv2/conv3 (4*128*8 blocks)

typedef __attribute__((ext_vector_type(8))) short short8;
typedef __attribute__((ext_vector_type(4))) float floatx4;

// round-half-up bf16 pack: 2 VALU ops, max err 0.5 ulp
__device__ __forceinline__ unsigned short f2bf(float f) {
  union { float f; unsigned int u; } v; v.f = f;
  return (unsigned short)((v.u + 0x8000u) >> 16);
}
// pack two fp32 -> bf16x2 (lo=a, hi=d): 5 VALU ops
__device__ __forceinline__ unsigned int pack2bf(float a, float d) {
  union { float f; unsigned int u; } va, vd; va.f = a; vd.f = d;
  return ((va.u + 0x8000u) >> 16) | ((vd.u + 0x8000u) & 0xffff0000u);
}
__device__ __forceinline__ float bf2f(unsigned short u) {
  union { unsigned int u; float f; } v; v.u = ((unsigned int)u) << 16;
  return v.f;
}

// ---- fused weight pre-swizzle for conv2+conv3: OIHW fp32 -> B-frag bf16 ---
__global__ __launch_bounds__(256) void prep_all(
    const float* __restrict__ w2, const float* __restrict__ w3,
    unsigned short* __restrict__ wf2, unsigned short* __restrict__ wf3)
{
  int idx = blockIdx.x * 256 + threadIdx.x;
  if (idx < 18432) {  // conv2: CIN=32, COUT=64, KC=1, NG=4
    const int j = idx & 7;
    const int lane = (idx >> 3) & 63;
    int rest = idx >> 9;
    const int ng = rest % 4;
    const int tap = rest / 4;
    const int cout = ng * 16 + (lane & 15);
    const int cin = ((lane >> 4) << 3) + j;
    wf2[idx] = f2bf(w2[((size_t)cout * 32 + cin) * 9 + tap]);
  } else {            // conv3: CIN=64, COUT=128, KC=2, NG=8
    idx -= 18432;
    if (idx >= 73728) return;
    const int j = idx & 7;
    const int lane = (idx >> 3) & 63;
    int rest = idx >> 9;
    const int ng = rest % 8; rest /= 8;
    const int kc = rest & 1;
    const int tap = rest >> 1;
    const int cout = ng * 16 + (lane & 15);
    const int cin = kc * 32 + ((lane >> 4) << 3) + j;
    wf3[idx] = f2bf(w3[((size_t)cout * 64 + cin) * 9 + tap]);
  }
}

// ---- conv1: 3->32, fp32 VALU, raw y1 (bias, NO bn) bf16 NHWC direct store -
__global__ __launch_bounds__(256) void conv1_kernel(
    const float* __restrict__ in, const float* __restrict__ wgt,
    const float* __restrict__ bias, unsigned short* __restrict__ out,
    float* __restrict__ partial)
{
  const int w = threadIdx.x, h = blockIdx.x, b = blockIdx.y;
  int off[9]; float msk[9];
  #pragma unroll
  for (int dh = -1; dh <= 1; ++dh)
    #pragma unroll
    for (int dw = -1; dw <= 1; ++dw) {
      int t9 = (dh + 1) * 3 + (dw + 1);
      int hh = h + dh, ww = w + dw;
      bool ok = (hh >= 0) && (hh < HH) && (ww >= 0) && (ww < WW);
      int hc = min(max(hh, 0), HH - 1), wc = min(max(ww, 0), WW - 1);
      off[t9] = hc * WW + wc;
      msk[t9] = ok ? 1.0f : 0.0f;
    }
  const float* inb = in + (size_t)b * 3 * HWSZ;
  float acc[32];
  #pragma unroll
  for (int c = 0; c < 32; ++c) acc[c] = bias[c];
  for (int ci = 0; ci < 3; ++ci) {
    const float* p = inb + (size_t)ci * HWSZ;
    float v[9];
    #pragma unroll
    for (int t = 0; t < 9; ++t) v[t] = p[off[t]] * msk[t];
    #pragma unroll
    for (int c = 0; c < 32; ++c) {
      const float* wr = wgt + ((size_t)c * 3 + ci) * 9;
      #pragma unroll
      for (int t = 0; t < 9; ++t) acc[c] = fmaf(wr[t], v[t], acc[c]);
    }
  }
  __shared__ float red[4][32][2];
  const int lane = threadIdx.x & 63, wv = threadIdx.x >> 6;
  #pragma unroll
  for (int c = 0; c < 32; ++c) {
    float s = acc[c], q = acc[c] * acc[c];
    #pragma unroll
    for (int o = 32; o > 0; o >>= 1) { s += __shfl_down(s, o); q += __shfl_down(q, o); }
    if (lane == 0) { red[wv][c][0] = s; red[wv][c][1] = q; }
  }
  uint4* o4 = (uint4*)(out + ((size_t)((b * 256 + h) * 256 + w)) * 32);
  #pragma unroll
  for (int i = 0; i < 4; ++i) {
    uint4 u;
    u.x = pack2bf(acc[8 * i + 0], acc[8 * i + 1]);
    u.y = pack2bf(acc[8 * i + 2], acc[8 * i + 3]);
    u.z = pack2bf(acc[8 * i + 4], acc[8 * i + 5]);
    u.w = pack2bf(acc[8 * i + 6], acc[8 * i + 7]);
    o4[i] = u;
  }
  __syncthreads();
  if (threadIdx.x < 64) {
    int c = threadIdx.x >> 1, j = threadIdx.x & 1;
    float r = red[0][c][j] + red[1][c][j] + red[2][c][j] + red[3][c][j];
    int pb = b * 256 + h;
    partial[((size_t)c * 2 + j) * 2048 + pb] = r;
  }
}

// ---- MFMA conv: 64px x 2 ROWS x COUT per block, PADDED affine LDS ---------
// RAW input; BN+lrelu fused into staging unpack. Stage 4 rows x 66 px once,
// one barrier, rows interleaved inside the k-step. LDS pixel stride =
// CIN+8 halfwords (R2 layout: measured 0 bank conflicts) -> every k-loop
// ds_read address is wave_base + compile-time constant (offset:imm),
// killing the per-access XOR/shift/add chains of the swizzled layout.
template<int CIN, int COUT, bool WRITE_OUT, int MINW>
__global__ __launch_bounds__(256, MINW) void conv_mfma(
    const unsigned short* __restrict__ in, const unsigned short* __restrict__ wf,
    const float* __restrict__ bias,
    const float* __restrict__ bn_sc, const float* __restrict__ bn_sh,
    unsigned short* __restrict__ out, float* __restrict__ partial)
{
  constexpr int KC = CIN / 32;
  constexpr int NG = COUT / 16;
  constexpr int NF = COUT / 32;       // n-frags per wave (2 n-waves)
  constexpr int CH8 = CIN / 8;        // 16B chunks per pixel
  constexpr int CH8_LOG = (CH8 == 4) ? 2 : 3;
  constexpr int CPAD = CIN + 8;       // padded pixel stride (halfwords)
  constexpr int CHUNKS = 4 * 66 * CH8;

  const int tid = threadIdx.x, lane = tid & 63, wv = tid >> 6;
  const int wave_m = wv >> 1, wave_n = wv & 1;
  const int h0 = blockIdx.y * 2, b = blockIdx.z, w0 = blockIdx.x * 64;
  const size_t inb = (size_t)b * HWSZ * CIN;

  __shared__ __align__(16) unsigned short lds[4 * 66 * CPAD];

  // stage 4 rows x 66 px, BN(scale/shift)+leakyReLU applied on unpack
  for (int c = tid; c < CHUNKS; c += 256) {
    const int r = c / (66 * CH8);
    const int rem = c - r * (66 * CH8);
    const int px = rem >> CH8_LOG, ck = rem & (CH8 - 1);
    const int hi = h0 + r - 1, wi = w0 - 1 + px;
    uint4 v = make_uint4(0u, 0u, 0u, 0u);
    if ((unsigned)hi < 256u && (unsigned)wi < 256u) {
      uint4 raw = *(const uint4*)&in[inb + ((size_t)hi * 256 + wi) * CIN + ck * 8];
      const float4 s0 = *(const float4*)&bn_sc[ck * 8];
      const float4 s1 = *(const float4*)&bn_sc[ck * 8 + 4];
      const float4 t0 = *(const float4*)&bn_sh[ck * 8];
      const float4 t1 = *(const float4*)&bn_sh[ck * 8 + 4];
      const float scs[8] = {s0.x, s0.y, s0.z, s0.w, s1.x, s1.y, s1.z, s1.w};
      const float shs[8] = {t0.x, t0.y, t0.z, t0.w, t1.x, t1.y, t1.z, t1.w};
      unsigned int* u = (unsigned int*)&raw;
      unsigned int* o = (unsigned int*)&v;
      #pragma unroll
      for (int p = 0; p < 4; ++p) {
        float a = bf2f((unsigned short)(u[p] & 0xffff));
        float d = bf2f((unsigned short)(u[p] >> 16));
        float ya = a * scs[2 * p] + shs[2 * p];
        float yd = d * scs[2 * p + 1] + shs[2 * p + 1];
        ya = fmaxf(ya, 0.01f * ya);
        yd = fmaxf(yd, 0.01f * yd);
        o[p] = pack2bf(ya, yd);
      }
    }
    *(uint4*)&lds[(r * 66 + px) * CPAD + ck * 8] = v;
  }
  __syncthreads();

  const int j15 = lane & 15, q4 = lane >> 4;
  const int base_px = wave_m * 32 + j15;
  // all k-loop reads = abase + compile-time constant (fits offset:imm)
  const unsigned short* abase = &lds[base_px * CPAD + q4 * 8];

  floatx4 acc[2][2][NF];  // [row][mf][nf]
  #pragma unroll
  for (int rr = 0; rr < 2; ++rr)
    #pragma unroll
    for (int mf = 0; mf < 2; ++mf)
      #pragma unroll
      for (int nf = 0; nf < NF; ++nf) acc[rr][mf][nf] = (floatx4){0.f, 0.f, 0.f, 0.f};

  #pragma unroll
  for (int dh = 0; dh < 3; ++dh) {
    #pragma unroll
    for (int dw = 0; dw < 3; ++dw) {
      #pragma unroll
      for (int kc = 0; kc < KC; ++kc) {
        const int tap = dh * 3 + dw;
        short8 bg[NF];
        #pragma unroll
        for (int nf = 0; nf < NF; ++nf)
          bg[nf] = *(const short8*)&wf[((((tap * KC + kc) * NG) + wave_n * NF + nf) * 64 + lane) * 8];
        #pragma unroll
        for (int rr = 0; rr < 2; ++rr) {
          short8 a[2];
          #pragma unroll
          for (int mf = 0; mf < 2; ++mf)
            a[mf] = *(const short8*)&abase[((rr + dh) * 66 + dw + mf * 16) * CPAD + kc * 32];
          #pragma unroll
          for (int mf = 0; mf < 2; ++mf)
            #pragma unroll
            for (int nf = 0; nf < NF; ++nf)
              acc[rr][mf][nf] = __builtin_amdgcn_mfma_f32_16x16x32_bf16(a[mf], bg[nf], acc[rr][mf][nf], 0, 0, 0);
        }
      }
    }
  }

  // epilogue: +bias, per-wave stats over both rows, optional bf16 NHWC store
  float bv[NF], sa[NF], qa[NF];
  #pragma unroll
  for (int nf = 0; nf < NF; ++nf) {
    bv[nf] = bias[wave_n * (COUT / 2) + nf * 16 + j15];
    sa[nf] = 0.f; qa[nf] = 0.f;
  }
  #pragma unroll
  for (int rr = 0; rr < 2; ++rr) {
    const size_t orow = ((size_t)(b * 256 + (h0 + rr)) * 256 + w0);
    #pragma unroll
    for (int nf = 0; nf < NF; ++nf) {
      const int ch = wave_n * (COUT / 2) + nf * 16 + j15;
      #pragma unroll
      for (int mf = 0; mf < 2; ++mf)
        #pragma unroll
        for (int r4 = 0; r4 < 4; ++r4) {
          float y = acc[rr][mf][nf][r4] + bv[nf];
          sa[nf] += y; qa[nf] += y * y;
          if constexpr (WRITE_OUT) {
            const int p = wave_m * 32 + mf * 16 + q4 * 4 + r4;
            out[(orow + p) * COUT + ch] = f2bf(y);
          }
        }
    }
  }

  __syncthreads();
  float* red = (float*)lds;  // [4][NF][16] sums, then [4][NF][16] sumsq
  #pragma unroll
  for (int nf = 0; nf < NF; ++nf) {
    float s = sa[nf], q = qa[nf];
    s += __shfl_xor(s, 16); s += __shfl_xor(s, 32);
    q += __shfl_xor(q, 16); q += __shfl_xor(q, 32);
    if (lane < 16) {
      red[(wv * NF + nf) * 16 + lane] = s;
      red[4 * NF * 16 + (wv * NF + nf) * 16 + lane] = q;
    }
  }
  __syncthreads();
  if (tid < COUT) {
    const int wn = tid / (COUT / 2), rr = tid % (COUT / 2);
    const int nf = rr >> 4, li = rr & 15;
    float s = red[(wn * NF + nf) * 16 + li] + red[((wn + 2) * NF + nf) * 16 + li];
    float q = red[4 * NF * 16 + (wn * NF + nf) * 16 + li] +
              red[4 * NF * 16 + ((wn + 2) * NF + nf) * 16 + li];
    const int blk = blockIdx.x + ((int)blockIdx.z * 128 + (int)blockIdx.y) * 4;  // 0..4095
    partial[((size_t)tid * 2 + 0) * NPB2 + blk] = s;
    partial[((size_t)tid * 2 + 1) * NPB2 + blk] = q;
  }
}

// ---- fold partials into scale/shift ---------------------------------------
__global__ __launch_bounds__(256) void reduce_stats(
    const float* __restrict__ partial, const float* __restrict__ gamma,
    const float* __restrict__ beta, float* __restrict__ scale,
    float* __restrict__ shift, int npb)
{
  const int c = blockIdx.x;
  float s = 0.f, q = 0.f;
  for (int i = threadIdx.x; i < npb; i += 256) {
    s += partial[((size_t)c * 2 + 0) * npb + i];
    q += partial[((size_t)c * 2 + 1) * npb + i];
  }
  #pragma unroll
  for (int o = 32; o > 0; o >>= 1) { s += __shfl_down(s, o); q += __shfl_down(q, o); }
  __shared__ float rs[4][2];
  const int lane = threadIdx.x & 63, wv = threadIdx.x >> 6;
  if (lane == 0) { rs[wv][0] = s; rs[wv][1] = q; }
  __syncthreads();
  if (threadIdx.x == 0) {
    s = rs[0][0] + rs[1][0] + rs[2][0] + rs[3][0];
    q = rs[0][1] + rs[1][1] + rs[2][1] + rs[3][1];
    const float N = (float)((size_t)BATCH * HWSZ);
    float mean = s / N;
    float var = q / N - mean * mean;
    float rstd = 1.0f / sqrtf(var + 1e-5f);
    float sc = gamma[c] * rstd;
    scale[c] = sc;
    shift[c] = beta[c] - mean * sc;
  }
}

// ---- fused outputs: patches (blocks 0..13) + encode (blocks 14..17) -------
// encode: conv3 at 8 pixels (n_xy) on RAW y2 (bn2+lrelu on read), bn3 at end.
__global__ __launch_bounds__(256) void outputs_kernel(
    const float* __restrict__ img, const int* __restrict__ axy,
    const int* __restrict__ pxy, const int* __restrict__ nxy,
    const unsigned short* __restrict__ y2, const float* __restrict__ wgt,
    const float* __restrict__ bias,
    const float* __restrict__ sc2, const float* __restrict__ sh2,
    const float* __restrict__ scale, const float* __restrict__ shift,
    float* __restrict__ out)
{
  if (blockIdx.x < 14) {
    const int i = blockIdx.x * 256 + threadIdx.x;
    if (i >= 3 * BATCH * 3 * 49) return;
    const int arr = i / 1176, r = i % 1176;
    const int b = r / 147, q = r % 147;
    const int c = q / 49, s = q % 49;
    const int ph = s / 7, pw = s % 7;
    const int* xy = (arr == 0) ? axy : ((arr == 1) ? pxy : nxy);
    const int x = xy[(b * 32 + 31) * 2 + 0];
    const int y = xy[(b * 32 + 31) * 2 + 1];
    out[i] = img[((size_t)(b * 3 + c) * HH + (x - 3 + ph)) * WW + (y - 3 + pw)];
  } else {
    const int b = (blockIdx.x - 14) * 2 + (threadIdx.x >> 7);
    const int co = threadIdx.x & 127;
    const int x = nxy[(b * 32 + 31) * 2 + 0];
    const int y = nxy[(b * 32 + 31) * 2 + 1];
    float acc = bias[co];
    for (int ci = 0; ci < 64; ++ci) {
      const float s2 = sc2[ci], h2 = sh2[ci];
      #pragma unroll
      for (int dh = -1; dh <= 1; ++dh)
        #pragma unroll
        for (int dw = -1; dw <= 1; ++dw) {
          float v = bf2f(y2[((size_t)(b * 256 + x + dh) * 256 + (y + dw)) * 64 + ci]);
          v = v * s2 + h2;
          v = fmaxf(v, 0.01f * v);
          acc = fmaf(wgt[((size_t)co * 64 + ci) * 9 + (dh + 1) * 3 + (dw + 1)], v, acc);
        }
    }
    const float yv = acc * scale[co] + shift[co];
    out[3528 + b * 128 + co] = fmaxf(yv, 0.01f * yv);
  }
}

extern "C" void kernel_launch(void* const* d_in, const int* in_sizes, int n_in,
                              void* d_out, int out_size, void* d_ws, size_t ws_size,
                              hipStream_t stream)
{
  const float* image = (const float*)d_in[0];
  const int* axy = (const int*)d_in[1];
  const int* pxy = (const int*)d_in[2];
  const int* nxy = (const int*)d_in[3];
  const float* c1w = (const float*)d_in[4];
  const float* c1b = (const float*)d_in[5];
  const float* g1 = (const float*)d_in[6];
  const float* b1 = (const float*)d_in[7];
  const float* c2w = (const float*)d_in[8];
  const float* c2b = (const float*)d_in[9];
  const float* g2 = (const float*)d_in[10];
  const float* b2 = (const float*)d_in[11];
  const float* c3w = (const float*)d_in[12];
  const float* c3b = (const float*)d_in[13];
  const float* g3 = (const float*)d_in[14];
  const float* b3 = (const float*)d_in[15];
  float* out = (float*)d_out;

  // workspace layout (~105 MB)
  unsigned short* zb1 = (unsigned short*)d_ws;            // raw y1, 16.78M bf16
  unsigned short* zb2 = zb1 + (size_t)8 * 32 * HWSZ;      // raw y2, 33.55M bf16
  unsigned short* wf2 = zb2 + (size_t)8 * 64 * HWSZ;      // 18432
  unsigned short* wf3 = wf2 + 18432;                      // 73728
  float* partial = (float*)(wf3 + 73728);                 // 128*2*4096 floats
  float* scale1 = partial + (size_t)128 * 2 * NPB2;
  float* shift1 = scale1 + 32;
  float* scale2 = shift1 + 32;
  float* shift2 = scale2 + 64;
  float* scale3 = shift2 + 64;
  float* shift3 = scale3 + 128;

  prep_all<<<360, 256, 0, stream>>>(c2w, c3w, wf2, wf3);

  // layer 1: 3 -> 32 (VALU fp32, raw bf16 NHWC out + stats)
  conv1_kernel<<<dim3(256, 8), 256, 0, stream>>>(image, c1w, c1b, zb1, partial);
  reduce_stats<<<32, 256, 0, stream>>>(partial, g1, b1, scale1, shift1, 2048);

  // layer 2: 32 -> 64 (MFMA; bn1+lrelu fused in staging; raw y2 out + stats)
  conv_mfma<32, 64, true, 2><<<dim3(4, 128, 8), 256, 0, stream>>>(
      zb1, wf2, c2b, scale1, shift1, zb2, partial);
  reduce_stats<<<64, 256, 0, stream>>>(partial, g2, b2, scale2, shift2, NPB2);

  // layer 3: 64 -> 128 (MFMA; bn2+lrelu fused in staging; stats only)
  conv_mfma<64, 128, false, 2><<<dim3(4, 128, 8), 256, 0, stream>>>(
      zb2, wf3, c3b, scale2, shift2, nullptr, partial);
  reduce_stats<<<128, 256, 0, stream>>>(partial, g3, b3, scale3, shift3, NPB2);

  // outputs: patches + encode fused (bn2 on reads, bn3 at end)
  outputs_kernel<<<18, 256, 0, stream>>>(image, axy, pxy, nxy, zb2, c3w, c3b,
                                         scale2, shift2, scale3, shift3, out);
}